// Round 5
// baseline (1435.627 us; speedup 1.0000x reference)
//
#include <hip/hip_runtime.h>

typedef __attribute__((ext_vector_type(8))) short bf16x8;
typedef __attribute__((ext_vector_type(4))) float f32x4;

__device__ __forceinline__ float silu_f(float x) {
  return x / (1.0f + __expf(-x));
}

__device__ __forceinline__ unsigned short f2bf(float f) {
  union { float f; unsigned int u; } x; x.f = f;
  unsigned int u = x.u + 0x7fffu + ((x.u >> 16) & 1u);  // RNE
  return (unsigned short)(u >> 16);
}

__device__ __forceinline__ float bf2f_lo(unsigned int packed) {
  return __uint_as_float(packed << 16);
}
__device__ __forceinline__ float bf2f_hi(unsigned int packed) {
  return __uint_as_float(packed & 0xffff0000u);
}

// Transpose+convert weights: Wm2(256x128 f32) -> Wm2T(128x256 bf16);
// Wc1(128x64 f32) -> Wc1T(64x128 bf16).
__global__ void prep_weights(const float* __restrict__ Wm2, const float* __restrict__ Wc1,
                             unsigned short* __restrict__ Wm2T, unsigned short* __restrict__ Wc1T)
{
  int i = blockIdx.x * 256 + threadIdx.x;
  if (i < 128 * 256) {
    int n = i >> 8, k = i & 255;
    Wm2T[i] = f2bf(Wm2[k * 128 + n]);
  }
  if (i < 64 * 128) {
    int n = i >> 7, k = i & 127;
    Wc1T[i] = f2bf(Wc1[k * 64 + n]);
  }
}

// ---- counting sort of edges by target ----
__global__ void count_edges(const int* __restrict__ etgt, int* __restrict__ cnt, int E) {
  int e = blockIdx.x * 256 + threadIdx.x;
  if (e < E) atomicAdd(&cnt[etgt[e]], 1);
}

// single block, 256 threads: exclusive prefix sum of cnt -> cursor
__global__ void scan_bins(const int* __restrict__ cnt, int* __restrict__ cursor, int n) {
  __shared__ int sums[256];
  int tid = threadIdx.x;
  int chunk = (n + 255) >> 8;
  int lo = tid * chunk, hi = min(lo + chunk, n);
  int s = 0;
  for (int i = lo; i < hi; i++) s += cnt[i];
  sums[tid] = s;
  __syncthreads();
  if (tid == 0) {
    int acc = 0;
    for (int i = 0; i < 256; i++) { int t = sums[i]; sums[i] = acc; acc += t; }
  }
  __syncthreads();
  int run = sums[tid];
  for (int i = lo; i < hi; i++) { int c = cnt[i]; cursor[i] = run; run += c; }
}

__global__ void scatter_edges(const int* __restrict__ etgt, int* __restrict__ cursor,
                              int* __restrict__ perm, int E) {
  int e = blockIdx.x * 256 + threadIdx.x;
  if (e < E) {
    int p = atomicAdd(&cursor[etgt[e]], 1);
    perm[p] = e;
  }
}

// C[M x 256] (bf16) = X1[M x 128] @ W1(128x256, ld=256) [+ X2 @ W2] [+ bias]
__global__ __launch_bounds__(256, 2) void node_pre(
    const float* __restrict__ X1, const float* __restrict__ W1,
    const float* __restrict__ X2, const float* __restrict__ W2,
    const float* __restrict__ bias, unsigned short* __restrict__ C, int M)
{
  __shared__ float xs[32][128];
  int row0 = blockIdx.x * 32;
  int c = threadIdx.x;
  float acc[32];
#pragma unroll
  for (int r = 0; r < 32; r++) acc[r] = 0.f;

  for (int pass = 0; pass < 2; ++pass) {
    const float* X = pass ? X2 : X1;
    const float* W = pass ? W2 : W1;
    if (X == nullptr) break;
    __syncthreads();
    for (int i = threadIdx.x; i < 32 * 32; i += 256) {
      int r = i >> 5, q = i & 31;
      int row = row0 + r;
      float4 v = make_float4(0.f, 0.f, 0.f, 0.f);
      if (row < M) v = ((const float4*)(X + (size_t)row * 128))[q];
      ((float4*)&xs[r][0])[q] = v;
    }
    __syncthreads();
    for (int k = 0; k < 128; k += 4) {
      float w0 = W[(size_t)(k + 0) * 256 + c];
      float w1 = W[(size_t)(k + 1) * 256 + c];
      float w2 = W[(size_t)(k + 2) * 256 + c];
      float w3 = W[(size_t)(k + 3) * 256 + c];
#pragma unroll
      for (int r = 0; r < 32; r++) {
        float4 x = *(const float4*)&xs[r][k];
        acc[r] = fmaf(x.x, w0, fmaf(x.y, w1, fmaf(x.z, w2, fmaf(x.w, w3, acc[r]))));
      }
    }
  }
  float bv = bias ? bias[c] : 0.f;
  for (int r = 0; r < 32; r++) {
    int row = row0 + r;
    if (row < M) C[(size_t)row * 256 + c] = f2bf(acc[r] + bv);
  }
}

// Per-edge MFMA kernel over target-sorted edges: 64 edges per 256-thread block.
#define HID_LD 264   // 256 + 8 bf16 pad
#define MSG_LD 136   // 128 + 8 bf16 pad (row = 272 B = 68 floats)
#define AGG_LD 132   // f32 ld for aggP (64*132*4 = 33792 B = hid region exactly)
__global__ __launch_bounds__(256, 3) void edge_mfma(
    const unsigned short* __restrict__ A, const unsigned short* __restrict__ B,
    const float* __restrict__ w1c,
    const unsigned short* __restrict__ Wm2T, const float* __restrict__ bm2,
    const unsigned short* __restrict__ Wc1T, const float* __restrict__ bc1,
    const float* __restrict__ Wc2, const float* __restrict__ bc2,
    const float* __restrict__ pos_src, const float* __restrict__ pos_tgt,
    const int* __restrict__ esrc, const int* __restrict__ etgt,
    const int* __restrict__ perm,
    float* __restrict__ agg, float* __restrict__ vel, int E)
{
  __shared__ int ss[64], ts[64], segs[64], segtgt[64];
  __shared__ int nsegS;
  __shared__ float rels[64][4];
  __shared__ float velP[64][3];
  __shared__ unsigned short hid[64 * HID_LD];   // aliased after phase 2: aggP f32 [64][AGG_LD]
  __shared__ unsigned short msgs[64 * MSG_LD];  // aliased per-row in phase 3: c1 f32 ld 68

  int tid = threadIdx.x;
  int e0 = blockIdx.x * 64;

  if (tid < 64) {  // exactly wave 0
    int e = e0 + tid;
    int s = 0, t = -1;
    if (e < E) { int eid = perm[e]; s = esrc[eid]; t = etgt[eid]; }
    ss[tid] = s; ts[tid] = t;
    int tc = t < 0 ? 0 : t;
    float rx = pos_tgt[(size_t)tc * 3 + 0] - pos_src[(size_t)s * 3 + 0];
    float ry = pos_tgt[(size_t)tc * 3 + 1] - pos_src[(size_t)s * 3 + 1];
    float rz = pos_tgt[(size_t)tc * 3 + 2] - pos_src[(size_t)s * 3 + 2];
    rels[tid][0] = rx; rels[tid][1] = ry; rels[tid][2] = rz;
    rels[tid][3] = rx * rx + ry * ry + rz * rz;
    // segment ids over sorted targets (wave-0 ballot)
    int tprev = __shfl_up(t, 1);
    int flag = (tid > 0 && t != tprev) ? 1 : 0;
    unsigned long long mask = __ballot(flag);
    int segid = (int)__popcll(mask & ((1ULL << tid) - 1ULL)) + flag;
    segs[tid] = segid;
    if (flag || tid == 0) segtgt[segid] = t;
    if (tid == 0) nsegS = (int)__popcll(mask) + 1;
  }
  __syncthreads();

  // phase 1: hid[r][c] = bf16(silu(A[s][c] + B[t][c] + sq*w1c[c])), c=0..255
  {
    int c2 = tid & 127;
    int r0 = (tid >> 7) * 32;
    float wv0 = w1c[2 * c2], wv1 = w1c[2 * c2 + 1];
#pragma unroll 4
    for (int rr = 0; rr < 32; rr++) {
      int r = r0 + rr;
      int s = ss[r];
      int t = ts[r]; t = t < 0 ? 0 : t;
      unsigned int av = *(const unsigned int*)&A[(size_t)s * 256 + 2 * c2];
      unsigned int bv = *(const unsigned int*)&B[(size_t)t * 256 + 2 * c2];
      float sq = rels[r][3];
      float v0 = silu_f(bf2f_lo(av) + bf2f_lo(bv) + sq * wv0);
      float v1 = silu_f(bf2f_hi(av) + bf2f_hi(bv) + sq * wv1);
      unsigned int pk = ((unsigned int)f2bf(v1) << 16) | (unsigned int)f2bf(v0);
      *(unsigned int*)&hid[r * HID_LD + 2 * c2] = pk;
    }
  }
  __syncthreads();

  int w = tid >> 6, lane = tid & 63;
  int l15 = lane & 15, lg = lane >> 4;
  int R0 = w * 16;

  // phase 2: msg(64x128) = silu(hid(64x256) @ Wm2(256x128) + bm2), MFMA
  f32x4 acc[8];
#pragma unroll
  for (int f = 0; f < 8; f++) acc[f] = (f32x4){0.f, 0.f, 0.f, 0.f};
  {
    const unsigned short* hrow = &hid[(R0 + l15) * HID_LD];
#pragma unroll
    for (int ks = 0; ks < 8; ks++) {
      int kb = ks * 32 + lg * 8;
      bf16x8 a = *(const bf16x8*)&hrow[kb];
#pragma unroll
      for (int f = 0; f < 8; f++) {
        bf16x8 b = *(const bf16x8*)&Wm2T[(f * 16 + l15) * 256 + kb];
        acc[f] = __builtin_amdgcn_mfma_f32_16x16x32_bf16(a, b, acc[f], 0, 0, 0);
      }
    }
  }
  __syncthreads();  // all waves done reading hid -> safe to alias as aggP

  float* aggP = (float*)hid;
  for (int i = tid; i < 64 * AGG_LD; i += 256) aggP[i] = 0.f;
  if (tid < 64) { velP[tid][0] = 0.f; velP[tid][1] = 0.f; velP[tid][2] = 0.f; }
  __syncthreads();

  // epilogue: msgs (bf16) + run-length segmented add into aggP (LDS atomics)
#pragma unroll
  for (int f = 0; f < 8; f++) {
    int col = f * 16 + l15;
    float bias = bm2[col];
    int curseg = -1; float runv = 0.f;
#pragma unroll
    for (int r = 0; r < 4; r++) {
      int row = R0 + lg * 4 + r;
      float v = silu_f(acc[f][r] + bias);
      msgs[row * MSG_LD + col] = f2bf(v);
      int sg = (e0 + row < E) ? segs[row] : -1;
      if (sg != curseg) {
        if (curseg >= 0) atomicAdd(&aggP[curseg * AGG_LD + col], runv);
        curseg = sg; runv = 0.f;
      }
      if (sg >= 0) runv += v;
    }
    if (curseg >= 0) atomicAdd(&aggP[curseg * AGG_LD + col], runv);
  }
  __syncthreads();

  // agg write-out: one global atomic per (segment, col)
  int nseg = nsegS;
  {
    int col = tid & 127;
    for (int sb = 0; sb < nseg; sb += 2) {
      int s = sb + (tid >> 7);
      if (s < nseg) {
        int t = segtgt[s];
        if (t >= 0) atomicAdd(&agg[(size_t)t * 128 + col], aggP[s * AGG_LD + col]);
      }
    }
  }

  // phase 3: c1(64x64) = silu(msg(64x128) @ Wc1(128x64) + bc1), MFMA
  f32x4 acc2[4];
#pragma unroll
  for (int f = 0; f < 4; f++) acc2[f] = (f32x4){0.f, 0.f, 0.f, 0.f};
  {
    const unsigned short* mrow = &msgs[(R0 + l15) * MSG_LD];
#pragma unroll
    for (int ks = 0; ks < 4; ks++) {
      int kb = ks * 32 + lg * 8;
      bf16x8 a = *(const bf16x8*)&mrow[kb];
#pragma unroll
      for (int f = 0; f < 4; f++) {
        bf16x8 b = *(const bf16x8*)&Wc1T[(f * 16 + l15) * 128 + kb];
        acc2[f] = __builtin_amdgcn_mfma_f32_16x16x32_bf16(a, b, acc2[f], 0, 0, 0);
      }
    }
  }
  // c1 aliases msgs row-for-row (272 B = 68 floats per row); within a wave all
  // msgs reads (ds_read, in program order above) precede these ds_writes, and
  // waves touch disjoint row ranges.
  float* c1 = (float*)msgs;
#pragma unroll
  for (int f = 0; f < 4; f++) {
    int col = f * 16 + l15;
    float bias = bc1[col];
#pragma unroll
    for (int r = 0; r < 4; r++) {
      int row = R0 + lg * 4 + r;
      c1[row * 68 + col] = silu_f(acc2[f][r] + bias);
    }
  }
  __syncthreads();

  // phase 4: wgt = tanh(c1 @ Wc2 + bc2); velP[seg] += wgt * rel
  {
    int row = tid >> 2, sub = tid & 3;
    const float* crow = &c1[row * 68 + sub * 16];
    float dot = 0.f;
#pragma unroll
    for (int k = 0; k < 16; k++) dot = fmaf(crow[k], Wc2[sub * 16 + k], dot);
    dot += __shfl_xor(dot, 1);
    dot += __shfl_xor(dot, 2);
    if (sub == 0 && e0 + row < E) {
      float wv = tanhf(dot + bc2[0]);
      int sg = segs[row];
      atomicAdd(&velP[sg][0], wv * rels[row][0]);
      atomicAdd(&velP[sg][1], wv * rels[row][1]);
      atomicAdd(&velP[sg][2], wv * rels[row][2]);
    }
  }
  __syncthreads();
  if (tid < 3 * nseg) {
    int s = tid / 3, k = tid - 3 * s;
    int t = segtgt[s];
    if (t >= 0) atomicAdd(&vel[(size_t)t * 3 + k], velP[s][k]);
  }
}

// Per-target update MLP + layernorm. 32 targets per 256-thread block.
__global__ __launch_bounds__(256, 2) void tgt_update(
    const float* __restrict__ h_tgt, const float* __restrict__ agg,
    const float* __restrict__ Wu1, const float* __restrict__ bu1,
    const float* __restrict__ Wu2, const float* __restrict__ bu2,
    const float* __restrict__ gamma, const float* __restrict__ beta,
    float* __restrict__ out, int M)
{
  __shared__ float ht[32][132];
  __shared__ float xs[32][132];
  int row0 = blockIdx.x * 32;
  int tid = threadIdx.x;

  for (int i = tid; i < 32 * 32; i += 256) {
    int r = i >> 5, q = i & 31;
    int row = row0 + r;
    float4 a = make_float4(0.f, 0.f, 0.f, 0.f), g = a;
    if (row < M) {
      a = ((const float4*)(h_tgt + (size_t)row * 128))[q];
      g = ((const float4*)(agg + (size_t)row * 128))[q];
    }
    ((float4*)&ht[r][0])[q] = a;
    ((float4*)&xs[r][0])[q] = g;
  }
  __syncthreads();

  int j = tid & 127;
  int rg = tid >> 7;
  float acc[16];
  {
    float b = bu1[j];
#pragma unroll
    for (int r = 0; r < 16; r++) acc[r] = b;
  }
  for (int k = 0; k < 128; k += 4) {
    float w0 = Wu1[(size_t)(k + 0) * 128 + j];
    float w1 = Wu1[(size_t)(k + 1) * 128 + j];
    float w2 = Wu1[(size_t)(k + 2) * 128 + j];
    float w3 = Wu1[(size_t)(k + 3) * 128 + j];
#pragma unroll
    for (int r = 0; r < 16; r++) {
      float4 x = *(const float4*)&ht[rg * 16 + r][k];
      acc[r] = fmaf(x.x, w0, fmaf(x.y, w1, fmaf(x.z, w2, fmaf(x.w, w3, acc[r]))));
    }
  }
  for (int k = 0; k < 128; k += 4) {
    float w0 = Wu1[(size_t)(128 + k + 0) * 128 + j];
    float w1 = Wu1[(size_t)(128 + k + 1) * 128 + j];
    float w2 = Wu1[(size_t)(128 + k + 2) * 128 + j];
    float w3 = Wu1[(size_t)(128 + k + 3) * 128 + j];
#pragma unroll
    for (int r = 0; r < 16; r++) {
      float4 x = *(const float4*)&xs[rg * 16 + r][k];
      acc[r] = fmaf(x.x, w0, fmaf(x.y, w1, fmaf(x.z, w2, fmaf(x.w, w3, acc[r]))));
    }
  }
#pragma unroll
  for (int r = 0; r < 16; r++) acc[r] = silu_f(acc[r]);
  __syncthreads();
#pragma unroll
  for (int r = 0; r < 16; r++) xs[rg * 16 + r][j] = acc[r];
  __syncthreads();

  float acc2[16];
  {
    float b = bu2[j];
#pragma unroll
    for (int r = 0; r < 16; r++) acc2[r] = b;
  }
  for (int k = 0; k < 128; k += 4) {
    float w0 = Wu2[(size_t)(k + 0) * 128 + j];
    float w1 = Wu2[(size_t)(k + 1) * 128 + j];
    float w2 = Wu2[(size_t)(k + 2) * 128 + j];
    float w3 = Wu2[(size_t)(k + 3) * 128 + j];
#pragma unroll
    for (int r = 0; r < 16; r++) {
      float4 x = *(const float4*)&xs[rg * 16 + r][k];
      acc2[r] = fmaf(x.x, w0, fmaf(x.y, w1, fmaf(x.z, w2, fmaf(x.w, w3, acc2[r]))));
    }
  }
  __syncthreads();
#pragma unroll
  for (int r = 0; r < 16; r++) xs[rg * 16 + r][j] = acc2[r] + ht[rg * 16 + r][j];
  __syncthreads();

  int row = tid >> 3, sub = tid & 7;
  float s = 0.f, s2 = 0.f;
#pragma unroll
  for (int q = 0; q < 16; q++) {
    float v = xs[row][sub * 16 + q];
    s += v; s2 += v * v;
  }
  for (int off = 1; off < 8; off <<= 1) {
    s += __shfl_xor(s, off, 64);
    s2 += __shfl_xor(s2, off, 64);
  }
  float mu = s * (1.f / 128.f);
  float var = s2 * (1.f / 128.f) - mu * mu;
  float rs = rsqrtf(var + 1e-5f);
  int orow = row0 + row;
  if (orow < M) {
#pragma unroll
    for (int q = 0; q < 16; q++) {
      int c = sub * 16 + q;
      out[(size_t)orow * 128 + c] = (xs[row][c] - mu) * rs * gamma[c] + beta[c];
    }
  }
}

extern "C" void kernel_launch(void* const* d_in, const int* in_sizes, int n_in,
                              void* d_out, int out_size, void* d_ws, size_t ws_size,
                              hipStream_t stream) {
  const float* h_src  = (const float*)d_in[0];
  const float* h_tgt  = (const float*)d_in[1];
  const float* pos_src = (const float*)d_in[2];
  const float* pos_tgt = (const float*)d_in[3];
  const float* t_emb  = (const float*)d_in[4];
  const float* W_m1 = (const float*)d_in[5];
  const float* b_m1 = (const float*)d_in[6];
  const float* W_m2 = (const float*)d_in[7];
  const float* b_m2 = (const float*)d_in[8];
  const float* W_c1 = (const float*)d_in[9];
  const float* b_c1 = (const float*)d_in[10];
  const float* W_c2 = (const float*)d_in[11];
  const float* b_c2 = (const float*)d_in[12];
  const float* W_u1 = (const float*)d_in[13];
  const float* b_u1 = (const float*)d_in[14];
  const float* W_u2 = (const float*)d_in[15];
  const float* b_u2 = (const float*)d_in[16];
  const float* gamma = (const float*)d_in[17];
  const float* beta  = (const float*)d_in[18];
  const int* esrc = (const int*)d_in[19];
  const int* etgt = (const int*)d_in[20];

  int n_src = in_sizes[0] / 128;
  int n_tgt = in_sizes[1] / 128;
  int E = in_sizes[19];

  // workspace layout
  unsigned short* A    = (unsigned short*)d_ws;                 // n_src*256 bf16
  unsigned short* B    = A + (size_t)n_src * 256;               // n_tgt*256 bf16
  unsigned short* Wm2T = B + (size_t)n_tgt * 256;               // 128*256 bf16
  unsigned short* Wc1T = Wm2T + 128 * 256;                      // 64*128 bf16
  float* agg  = (float*)(Wc1T + 64 * 128);                      // n_tgt*128 f32
  int* cnt    = (int*)(agg + (size_t)n_tgt * 128);              // n_tgt
  int* cursor = cnt + n_tgt;                                    // n_tgt
  int* perm   = cursor + n_tgt;                                 // E
  float* out_h = (float*)d_out;                                 // n_tgt x 128
  float* vel = out_h + (size_t)n_tgt * 128;                     // n_tgt x 3

  hipMemsetAsync(agg, 0, (size_t)n_tgt * 128 * sizeof(float), stream);
  hipMemsetAsync(vel, 0, (size_t)n_tgt * 3 * sizeof(float), stream);
  hipMemsetAsync(cnt, 0, (size_t)n_tgt * sizeof(int), stream);

  dim3 blk(256);
  prep_weights<<<128, blk, 0, stream>>>(W_m2, W_c1, Wm2T, Wc1T);
  count_edges<<<(E + 255) / 256, blk, 0, stream>>>(etgt, cnt, E);
  scan_bins<<<1, blk, 0, stream>>>(cnt, cursor, n_tgt);
  scatter_edges<<<(E + 255) / 256, blk, 0, stream>>>(etgt, cursor, perm, E);
  node_pre<<<(n_src + 31) / 32, blk, 0, stream>>>(
      h_src, W_m1, nullptr, nullptr, nullptr, A, n_src);
  node_pre<<<(n_tgt + 31) / 32, blk, 0, stream>>>(
      h_tgt, W_m1 + 128 * 256, t_emb, W_m1 + 257 * 256, b_m1, B, n_tgt);
  edge_mfma<<<(E + 63) / 64, blk, 0, stream>>>(
      A, B, W_m1 + 256 * 256, Wm2T, b_m2, Wc1T, b_c1, W_c2, b_c2,
      pos_src, pos_tgt, esrc, etgt, perm, agg, vel, E);
  tgt_update<<<(n_tgt + 31) / 32, blk, 0, stream>>>(
      h_tgt, agg, W_u1, b_u1, W_u2, b_u2, gamma, beta, out_h, n_tgt);
}

// Round 7
// 1300.987 us; speedup vs baseline: 1.1035x; 1.1035x over previous
//
#include <hip/hip_runtime.h>

typedef __attribute__((ext_vector_type(8))) short bf16x8;
typedef __attribute__((ext_vector_type(4))) float f32x4;

__device__ __forceinline__ float silu_f(float x) {
  return x / (1.0f + __expf(-x));
}

__device__ __forceinline__ unsigned short f2bf(float f) {
  union { float f; unsigned int u; } x; x.f = f;
  unsigned int u = x.u + 0x7fffu + ((x.u >> 16) & 1u);  // RNE
  return (unsigned short)(u >> 16);
}

__device__ __forceinline__ float bfs2f(unsigned short s) {
  return __uint_as_float((unsigned int)s << 16);
}

// Transpose+convert weights: Wm2(256x128 f32) -> Wm2T(128x256 bf16);
// Wc1(128x64 f32) -> Wc1T(64x128 bf16).
__global__ void prep_weights(const float* __restrict__ Wm2, const float* __restrict__ Wc1,
                             unsigned short* __restrict__ Wm2T, unsigned short* __restrict__ Wc1T)
{
  int i = blockIdx.x * 256 + threadIdx.x;
  if (i < 128 * 256) {
    int n = i >> 8, k = i & 255;
    Wm2T[i] = f2bf(Wm2[k * 128 + n]);
  }
  if (i < 64 * 128) {
    int n = i >> 7, k = i & 127;
    Wc1T[i] = f2bf(Wc1[k * 64 + n]);
  }
}

// ---- counting sort of edges by target ----
__global__ void count_edges(const int* __restrict__ etgt, int* __restrict__ cnt, int E) {
  int e = blockIdx.x * 256 + threadIdx.x;
  if (e < E) atomicAdd(&cnt[etgt[e]], 1);
}

// single block, 256 threads: exclusive prefix sum of cnt -> cursor
__global__ void scan_bins(const int* __restrict__ cnt, int* __restrict__ cursor, int n) {
  __shared__ int sums[256];
  int tid = threadIdx.x;
  int chunk = (n + 255) >> 8;
  int lo = tid * chunk, hi = min(lo + chunk, n);
  int s = 0;
  for (int i = lo; i < hi; i++) s += cnt[i];
  sums[tid] = s;
  __syncthreads();
  if (tid == 0) {
    int acc = 0;
    for (int i = 0; i < 256; i++) { int t = sums[i]; sums[i] = acc; acc += t; }
  }
  __syncthreads();
  int run = sums[tid];
  for (int i = lo; i < hi; i++) { int c = cnt[i]; cursor[i] = run; run += c; }
}

__global__ void scatter_edges(const int* __restrict__ etgt, int* __restrict__ cursor,
                              int* __restrict__ perm, int E) {
  int e = blockIdx.x * 256 + threadIdx.x;
  if (e < E) {
    int p = atomicAdd(&cursor[etgt[e]], 1);
    perm[p] = e;
  }
}

// C[M x 256] (bf16) = X1[M x 128] @ W1(128x256, ld=256) [+ X2 @ W2] [+ bias]
__global__ __launch_bounds__(256, 2) void node_pre(
    const float* __restrict__ X1, const float* __restrict__ W1,
    const float* __restrict__ X2, const float* __restrict__ W2,
    const float* __restrict__ bias, unsigned short* __restrict__ C, int M)
{
  __shared__ float xs[32][128];
  int row0 = blockIdx.x * 32;
  int c = threadIdx.x;
  float acc[32];
#pragma unroll
  for (int r = 0; r < 32; r++) acc[r] = 0.f;

  for (int pass = 0; pass < 2; ++pass) {
    const float* X = pass ? X2 : X1;
    const float* W = pass ? W2 : W1;
    if (X == nullptr) break;
    __syncthreads();
    for (int i = threadIdx.x; i < 32 * 32; i += 256) {
      int r = i >> 5, q = i & 31;
      int row = row0 + r;
      float4 v = make_float4(0.f, 0.f, 0.f, 0.f);
      if (row < M) v = ((const float4*)(X + (size_t)row * 128))[q];
      ((float4*)&xs[r][0])[q] = v;
    }
    __syncthreads();
    for (int k = 0; k < 128; k += 4) {
      float w0 = W[(size_t)(k + 0) * 256 + c];
      float w1 = W[(size_t)(k + 1) * 256 + c];
      float w2 = W[(size_t)(k + 2) * 256 + c];
      float w3 = W[(size_t)(k + 3) * 256 + c];
#pragma unroll
      for (int r = 0; r < 32; r++) {
        float4 x = *(const float4*)&xs[r][k];
        acc[r] = fmaf(x.x, w0, fmaf(x.y, w1, fmaf(x.z, w2, fmaf(x.w, w3, acc[r]))));
      }
    }
  }
  float bv = bias ? bias[c] : 0.f;
  for (int r = 0; r < 32; r++) {
    int row = row0 + r;
    if (row < M) C[(size_t)row * 256 + c] = f2bf(acc[r] + bv);
  }
}

// Per-edge MFMA kernel over target-sorted edges: 64 edges per 256-thread block.
// Register-direct phase1: each lane computes its own MFMA A-fragment of the
// hidden layer (row R0+l15, cols ks*32+lg*8..+7) straight from gathered A/B
// rows -- no hid LDS, no phase-1 barrier.
#define MSG_LD 136   // 128 + 8 bf16 pad (row = 272 B = 68 floats)
__global__ __launch_bounds__(256, 6) void edge_mfma(
    const unsigned short* __restrict__ A, const unsigned short* __restrict__ B,
    const float* __restrict__ w1c,
    const unsigned short* __restrict__ Wm2T, const float* __restrict__ bm2,
    const unsigned short* __restrict__ Wc1T, const float* __restrict__ bc1,
    const float* __restrict__ Wc2, const float* __restrict__ bc2,
    const float* __restrict__ pos_src, const float* __restrict__ pos_tgt,
    const int* __restrict__ esrc, const int* __restrict__ etgt,
    const int* __restrict__ perm,
    float* __restrict__ agg, float* __restrict__ vel, int E)
{
  __shared__ int ss[64], ts[64], segs[64], segtgt[64];
  __shared__ int nsegS;
  __shared__ float rels[64][4];
  __shared__ float velP[64][3];
  __shared__ float w1cS[256];
  __shared__ unsigned short msgs[64 * MSG_LD];  // phase3 aliases rows as c1 f32 (ld 68)

  int tid = threadIdx.x;
  int e0 = blockIdx.x * 64;

  w1cS[tid] = w1c[tid];
  if (tid < 64) {  // exactly wave 0
    int e = e0 + tid;
    int s = 0, t = -1;
    if (e < E) { int eid = perm[e]; s = esrc[eid]; t = etgt[eid]; }
    ss[tid] = s; ts[tid] = t;
    int tc = t < 0 ? 0 : t;
    float rx = pos_tgt[(size_t)tc * 3 + 0] - pos_src[(size_t)s * 3 + 0];
    float ry = pos_tgt[(size_t)tc * 3 + 1] - pos_src[(size_t)s * 3 + 1];
    float rz = pos_tgt[(size_t)tc * 3 + 2] - pos_src[(size_t)s * 3 + 2];
    rels[tid][0] = rx; rels[tid][1] = ry; rels[tid][2] = rz;
    rels[tid][3] = rx * rx + ry * ry + rz * rz;
    velP[tid][0] = 0.f; velP[tid][1] = 0.f; velP[tid][2] = 0.f;
    // segment ids over sorted targets (wave-0 ballot)
    int tprev = __shfl_up(t, 1);
    int flag = (tid > 0 && t != tprev) ? 1 : 0;
    unsigned long long mask = __ballot(flag);
    int segid = (int)__popcll(mask & ((1ULL << tid) - 1ULL)) + flag;
    segs[tid] = segid;
    if (flag || tid == 0) segtgt[segid] = t;
    if (tid == 0) nsegS = (int)__popcll(mask) + 1;
  }
  __syncthreads();

  int w = tid >> 6, lane = tid & 63;
  int l15 = lane & 15, lg = lane >> 4;
  int R0 = w * 16;

  // ---- fused phase 1+2: per-lane hidden fragment in registers + MFMA ----
  int hrow = R0 + l15;                       // this lane's hidden-layer row
  int s_n = ss[hrow];
  int t_n = ts[hrow] < 0 ? 0 : ts[hrow];
  float sq = rels[hrow][3];
  const unsigned short* Arow = &A[(size_t)s_n * 256];
  const unsigned short* Brow = &B[(size_t)t_n * 256];

  f32x4 acc[8];
#pragma unroll
  for (int f = 0; f < 8; f++) acc[f] = (f32x4){0.f, 0.f, 0.f, 0.f};

#pragma unroll
  for (int ks = 0; ks < 8; ks++) {
    int c0 = ks * 32 + lg * 8;
    bf16x8 av = *(const bf16x8*)&Arow[c0];
    bf16x8 bv = *(const bf16x8*)&Brow[c0];
    bf16x8 a;
#pragma unroll
    for (int j = 0; j < 8; j++) {
      float h = silu_f(bfs2f((unsigned short)av[j]) + bfs2f((unsigned short)bv[j])
                       + sq * w1cS[c0 + j]);
      a[j] = (short)f2bf(h);
    }
#pragma unroll
    for (int f = 0; f < 8; f++) {
      bf16x8 b = *(const bf16x8*)&Wm2T[(f * 16 + l15) * 256 + c0];
      acc[f] = __builtin_amdgcn_mfma_f32_16x16x32_bf16(a, b, acc[f], 0, 0, 0);
    }
  }

  // epilogue: silu+bias -> msgs (bf16, LDS) + run-length merged global agg atomics
#pragma unroll
  for (int f = 0; f < 8; f++) {
    int col = f * 16 + l15;
    float bias = bm2[col];
    int curseg = -1; float runv = 0.f;
#pragma unroll
    for (int r = 0; r < 4; r++) {
      int row = R0 + lg * 4 + r;
      float v = silu_f(acc[f][r] + bias);
      msgs[row * MSG_LD + col] = f2bf(v);
      int sg = (e0 + row < E) ? segs[row] : -1;
      if (sg != curseg) {
        if (curseg >= 0)
          atomicAdd(&agg[(size_t)segtgt[curseg] * 128 + col], runv);
        curseg = sg; runv = 0.f;
      }
      if (sg >= 0) runv += v;
    }
    if (curseg >= 0)
      atomicAdd(&agg[(size_t)segtgt[curseg] * 128 + col], runv);
  }
  __syncthreads();

  // phase 3: c1(64x64) = silu(msg(64x128) @ Wc1(128x64) + bc1), MFMA
  f32x4 acc2[4];
#pragma unroll
  for (int f = 0; f < 4; f++) acc2[f] = (f32x4){0.f, 0.f, 0.f, 0.f};
  {
    const unsigned short* mrow = &msgs[hrow * MSG_LD];
#pragma unroll
    for (int ks = 0; ks < 4; ks++) {
      int kb = ks * 32 + lg * 8;
      bf16x8 a = *(const bf16x8*)&mrow[kb];
#pragma unroll
      for (int f = 0; f < 4; f++) {
        bf16x8 b = *(const bf16x8*)&Wc1T[(f * 16 + l15) * 128 + kb];
        acc2[f] = __builtin_amdgcn_mfma_f32_16x16x32_bf16(a, b, acc2[f], 0, 0, 0);
      }
    }
  }
  // c1 aliases msgs row-for-row (272 B = 68 floats per row); within a wave all
  // msgs reads (program order above) precede these writes; waves touch
  // disjoint row ranges.
  float* c1 = (float*)msgs;
#pragma unroll
  for (int f = 0; f < 4; f++) {
    int col = f * 16 + l15;
    float bias = bc1[col];
#pragma unroll
    for (int r = 0; r < 4; r++) {
      int row = R0 + lg * 4 + r;
      c1[row * 68 + col] = silu_f(acc2[f][r] + bias);
    }
  }
  __syncthreads();

  // phase 4: wgt = tanh(c1 @ Wc2 + bc2); velP[seg] += wgt * rel
  {
    int row = tid >> 2, sub = tid & 3;
    const float* crow = &c1[row * 68 + sub * 16];
    float dot = 0.f;
#pragma unroll
    for (int k = 0; k < 16; k++) dot = fmaf(crow[k], Wc2[sub * 16 + k], dot);
    dot += __shfl_xor(dot, 1);
    dot += __shfl_xor(dot, 2);
    if (sub == 0 && e0 + row < E) {
      float wv = tanhf(dot + bc2[0]);
      int sg = segs[row];
      atomicAdd(&velP[sg][0], wv * rels[row][0]);
      atomicAdd(&velP[sg][1], wv * rels[row][1]);
      atomicAdd(&velP[sg][2], wv * rels[row][2]);
    }
  }
  __syncthreads();
  int nseg = nsegS;
  if (tid < 3 * nseg) {
    int s = tid / 3, k = tid - 3 * s;
    int t = segtgt[s];
    if (t >= 0) atomicAdd(&vel[(size_t)t * 3 + k], velP[s][k]);
  }
}

// Per-target update MLP + layernorm. 32 targets per 256-thread block.
__global__ __launch_bounds__(256, 2) void tgt_update(
    const float* __restrict__ h_tgt, const float* __restrict__ agg,
    const float* __restrict__ Wu1, const float* __restrict__ bu1,
    const float* __restrict__ Wu2, const float* __restrict__ bu2,
    const float* __restrict__ gamma, const float* __restrict__ beta,
    float* __restrict__ out, int M)
{
  __shared__ float ht[32][132];
  __shared__ float xs[32][132];
  int row0 = blockIdx.x * 32;
  int tid = threadIdx.x;

  for (int i = tid; i < 32 * 32; i += 256) {
    int r = i >> 5, q = i & 31;
    int row = row0 + r;
    float4 a = make_float4(0.f, 0.f, 0.f, 0.f), g = a;
    if (row < M) {
      a = ((const float4*)(h_tgt + (size_t)row * 128))[q];
      g = ((const float4*)(agg + (size_t)row * 128))[q];
    }
    ((float4*)&ht[r][0])[q] = a;
    ((float4*)&xs[r][0])[q] = g;
  }
  __syncthreads();

  int j = tid & 127;
  int rg = tid >> 7;
  float acc[16];
  {
    float b = bu1[j];
#pragma unroll
    for (int r = 0; r < 16; r++) acc[r] = b;
  }
  for (int k = 0; k < 128; k += 4) {
    float w0 = Wu1[(size_t)(k + 0) * 128 + j];
    float w1 = Wu1[(size_t)(k + 1) * 128 + j];
    float w2 = Wu1[(size_t)(k + 2) * 128 + j];
    float w3 = Wu1[(size_t)(k + 3) * 128 + j];
#pragma unroll
    for (int r = 0; r < 16; r++) {
      float4 x = *(const float4*)&ht[rg * 16 + r][k];
      acc[r] = fmaf(x.x, w0, fmaf(x.y, w1, fmaf(x.z, w2, fmaf(x.w, w3, acc[r]))));
    }
  }
  for (int k = 0; k < 128; k += 4) {
    float w0 = Wu1[(size_t)(128 + k + 0) * 128 + j];
    float w1 = Wu1[(size_t)(128 + k + 1) * 128 + j];
    float w2 = Wu1[(size_t)(128 + k + 2) * 128 + j];
    float w3 = Wu1[(size_t)(128 + k + 3) * 128 + j];
#pragma unroll
    for (int r = 0; r < 16; r++) {
      float4 x = *(const float4*)&xs[rg * 16 + r][k];
      acc[r] = fmaf(x.x, w0, fmaf(x.y, w1, fmaf(x.z, w2, fmaf(x.w, w3, acc[r]))));
    }
  }
#pragma unroll
  for (int r = 0; r < 16; r++) acc[r] = silu_f(acc[r]);
  __syncthreads();
#pragma unroll
  for (int r = 0; r < 16; r++) xs[rg * 16 + r][j] = acc[r];
  __syncthreads();

  float acc2[16];
  {
    float b = bu2[j];
#pragma unroll
    for (int r = 0; r < 16; r++) acc2[r] = b;
  }
  for (int k = 0; k < 128; k += 4) {
    float w0 = Wu2[(size_t)(k + 0) * 128 + j];
    float w1 = Wu2[(size_t)(k + 1) * 128 + j];
    float w2 = Wu2[(size_t)(k + 2) * 128 + j];
    float w3 = Wu2[(size_t)(k + 3) * 128 + j];
#pragma unroll
    for (int r = 0; r < 16; r++) {
      float4 x = *(const float4*)&xs[rg * 16 + r][k];
      acc2[r] = fmaf(x.x, w0, fmaf(x.y, w1, fmaf(x.z, w2, fmaf(x.w, w3, acc2[r]))));
    }
  }
  __syncthreads();
#pragma unroll
  for (int r = 0; r < 16; r++) xs[rg * 16 + r][j] = acc2[r] + ht[rg * 16 + r][j];
  __syncthreads();

  int row = tid >> 3, sub = tid & 7;
  float s = 0.f, s2 = 0.f;
#pragma unroll
  for (int q = 0; q < 16; q++) {
    float v = xs[row][sub * 16 + q];
    s += v; s2 += v * v;
  }
  for (int off = 1; off < 8; off <<= 1) {
    s += __shfl_xor(s, off, 64);
    s2 += __shfl_xor(s2, off, 64);
  }
  float mu = s * (1.f / 128.f);
  float var = s2 * (1.f / 128.f) - mu * mu;
  float rs = rsqrtf(var + 1e-5f);
  int orow = row0 + row;
  if (orow < M) {
#pragma unroll
    for (int q = 0; q < 16; q++) {
      int c = sub * 16 + q;
      out[(size_t)orow * 128 + c] = (xs[row][c] - mu) * rs * gamma[c] + beta[c];
    }
  }
}

extern "C" void kernel_launch(void* const* d_in, const int* in_sizes, int n_in,
                              void* d_out, int out_size, void* d_ws, size_t ws_size,
                              hipStream_t stream) {
  const float* h_src  = (const float*)d_in[0];
  const float* h_tgt  = (const float*)d_in[1];
  const float* pos_src = (const float*)d_in[2];
  const float* pos_tgt = (const float*)d_in[3];
  const float* t_emb  = (const float*)d_in[4];
  const float* W_m1 = (const float*)d_in[5];
  const float* b_m1 = (const float*)d_in[6];
  const float* W_m2 = (const float*)d_in[7];
  const float* b_m2 = (const float*)d_in[8];
  const float* W_c1 = (const float*)d_in[9];
  const float* b_c1 = (const float*)d_in[10];
  const float* W_c2 = (const float*)d_in[11];
  const float* b_c2 = (const float*)d_in[12];
  const float* W_u1 = (const float*)d_in[13];
  const float* b_u1 = (const float*)d_in[14];
  const float* W_u2 = (const float*)d_in[15];
  const float* b_u2 = (const float*)d_in[16];
  const float* gamma = (const float*)d_in[17];
  const float* beta  = (const float*)d_in[18];
  const int* esrc = (const int*)d_in[19];
  const int* etgt = (const int*)d_in[20];

  int n_src = in_sizes[0] / 128;
  int n_tgt = in_sizes[1] / 128;
  int E = in_sizes[19];

  // workspace layout
  unsigned short* A    = (unsigned short*)d_ws;                 // n_src*256 bf16
  unsigned short* B    = A + (size_t)n_src * 256;               // n_tgt*256 bf16
  unsigned short* Wm2T = B + (size_t)n_tgt * 256;               // 128*256 bf16
  unsigned short* Wc1T = Wm2T + 128 * 256;                      // 64*128 bf16
  float* agg  = (float*)(Wc1T + 64 * 128);                      // n_tgt*128 f32
  int* cnt    = (int*)(agg + (size_t)n_tgt * 128);              // n_tgt
  int* cursor = cnt + n_tgt;                                    // n_tgt
  int* perm   = cursor + n_tgt;                                 // E
  float* out_h = (float*)d_out;                                 // n_tgt x 128
  float* vel = out_h + (size_t)n_tgt * 128;                     // n_tgt x 3

  hipMemsetAsync(agg, 0, (size_t)n_tgt * 128 * sizeof(float), stream);
  hipMemsetAsync(vel, 0, (size_t)n_tgt * 3 * sizeof(float), stream);
  hipMemsetAsync(cnt, 0, (size_t)n_tgt * sizeof(int), stream);

  dim3 blk(256);
  prep_weights<<<128, blk, 0, stream>>>(W_m2, W_c1, Wm2T, Wc1T);
  count_edges<<<(E + 255) / 256, blk, 0, stream>>>(etgt, cnt, E);
  scan_bins<<<1, blk, 0, stream>>>(cnt, cursor, n_tgt);
  scatter_edges<<<(E + 255) / 256, blk, 0, stream>>>(etgt, cursor, perm, E);
  node_pre<<<(n_src + 31) / 32, blk, 0, stream>>>(
      h_src, W_m1, nullptr, nullptr, nullptr, A, n_src);
  node_pre<<<(n_tgt + 31) / 32, blk, 0, stream>>>(
      h_tgt, W_m1 + 128 * 256, t_emb, W_m1 + 257 * 256, b_m1, B, n_tgt);
  edge_mfma<<<(E + 63) / 64, blk, 0, stream>>>(
      A, B, W_m1 + 256 * 256, Wm2T, b_m2, Wc1T, b_c1, W_c2, b_c2,
      pos_src, pos_tgt, esrc, etgt, perm, agg, vel, E);
  tgt_update<<<(n_tgt + 31) / 32, blk, 0, stream>>>(
      h_tgt, agg, W_u1, b_u1, W_u2, b_u2, gamma, beta, out_h, n_tgt);
}

// Round 9
// 1181.149 us; speedup vs baseline: 1.2154x; 1.1015x over previous
//
#include <hip/hip_runtime.h>

typedef __attribute__((ext_vector_type(8))) short bf16x8;
typedef __attribute__((ext_vector_type(4))) float f32x4;

__device__ __forceinline__ float silu_f(float x) {
  return x / (1.0f + __expf(-x));
}

__device__ __forceinline__ unsigned short f2bf(float f) {
  union { float f; unsigned int u; } x; x.f = f;
  unsigned int u = x.u + 0x7fffu + ((x.u >> 16) & 1u);  // RNE
  return (unsigned short)(u >> 16);
}

__device__ __forceinline__ float bfs2f(unsigned short s) {
  return __uint_as_float((unsigned int)s << 16);
}

// Transpose+convert all weights to bf16 [n][k] layouts for MFMA B-operands.
// Wm2(256x128) -> Wm2T[128][256]; Wc1(128x64) -> Wc1T[64][128];
// W_m1 rows 0-127 -> W1aT[256][128], rows 128-255 -> W1bT[256][128],
// rows 257-384 -> W1dT[256][128].
__global__ void prep_weights(const float* __restrict__ Wm2, const float* __restrict__ Wc1,
                             const float* __restrict__ Wm1,
                             unsigned short* __restrict__ Wm2T, unsigned short* __restrict__ Wc1T,
                             unsigned short* __restrict__ W1aT, unsigned short* __restrict__ W1bT,
                             unsigned short* __restrict__ W1dT)
{
  int i = blockIdx.x * 256 + threadIdx.x;   // grid covers 32768
  if (i < 128 * 256) {
    int n = i >> 8, k = i & 255;
    Wm2T[i] = f2bf(Wm2[k * 128 + n]);
  }
  if (i < 64 * 128) {
    int n = i >> 7, k = i & 127;
    Wc1T[i] = f2bf(Wc1[k * 64 + n]);
  }
  if (i < 256 * 128) {
    int n = i >> 7, k = i & 127;
    W1aT[i] = f2bf(Wm1[(size_t)k * 256 + n]);
    W1bT[i] = f2bf(Wm1[(size_t)(128 + k) * 256 + n]);
    W1dT[i] = f2bf(Wm1[(size_t)(257 + k) * 256 + n]);
  }
}

// ---- counting sort of edges by target ----
__global__ void count_edges(const int* __restrict__ etgt, int* __restrict__ cnt, int E) {
  int e = blockIdx.x * 256 + threadIdx.x;
  if (e < E) atomicAdd(&cnt[etgt[e]], 1);
}

__global__ void scan_bins(const int* __restrict__ cnt, int* __restrict__ cursor, int n) {
  __shared__ int sums[256];
  int tid = threadIdx.x;
  int chunk = (n + 255) >> 8;
  int lo = tid * chunk, hi = min(lo + chunk, n);
  int s = 0;
  for (int i = lo; i < hi; i++) s += cnt[i];
  sums[tid] = s;
  __syncthreads();
  if (tid == 0) {
    int acc = 0;
    for (int i = 0; i < 256; i++) { int t = sums[i]; sums[i] = acc; acc += t; }
  }
  __syncthreads();
  int run = sums[tid];
  for (int i = lo; i < hi; i++) { int c = cnt[i]; cursor[i] = run; run += c; }
}

__global__ void scatter_edges(const int* __restrict__ etgt, int* __restrict__ cursor,
                              int* __restrict__ perm, int E) {
  int e = blockIdx.x * 256 + threadIdx.x;
  if (e < E) {
    int p = atomicAdd(&cursor[etgt[e]], 1);
    perm[p] = e;
  }
}

// MFMA node table builder: C[M x 256] bf16 = X1@W1T^T [+ X2@W2T^T] [+ bias].
// WT layout: WT[n*128+k] = W[k][n] bf16. 64 rows/block, 4 waves x 16 rows.
__global__ __launch_bounds__(256, 4) void node_mfma(
    const float* __restrict__ X1, const unsigned short* __restrict__ W1T,
    const float* __restrict__ X2, const unsigned short* __restrict__ W2T,
    const float* __restrict__ bias, unsigned short* __restrict__ C, int M)
{
  int tid = threadIdx.x;
  int w = tid >> 6, lane = tid & 63;
  int l15 = lane & 15, lg = lane >> 4;
  int grow = blockIdx.x * 64 + w * 16 + l15;   // this lane's input row
  int rowc = grow < M ? grow : 0;

  f32x4 acc[16];
#pragma unroll
  for (int f = 0; f < 16; f++) acc[f] = (f32x4){0.f, 0.f, 0.f, 0.f};

  for (int pass = 0; pass < 2; ++pass) {
    const float* X = pass ? X2 : X1;
    const unsigned short* WT = pass ? W2T : W1T;
    if (X == nullptr) break;
    const float* Xrow = X + (size_t)rowc * 128;
#pragma unroll
    for (int ks = 0; ks < 4; ks++) {
      int c0 = ks * 32 + lg * 8;
      float4 x0 = *(const float4*)&Xrow[c0];
      float4 x1 = *(const float4*)&Xrow[c0 + 4];
      bf16x8 a;
      a[0] = (short)f2bf(x0.x); a[1] = (short)f2bf(x0.y);
      a[2] = (short)f2bf(x0.z); a[3] = (short)f2bf(x0.w);
      a[4] = (short)f2bf(x1.x); a[5] = (short)f2bf(x1.y);
      a[6] = (short)f2bf(x1.z); a[7] = (short)f2bf(x1.w);
#pragma unroll
      for (int f = 0; f < 16; f++) {
        bf16x8 b = *(const bf16x8*)&WT[(size_t)(f * 16 + l15) * 128 + c0];
        acc[f] = __builtin_amdgcn_mfma_f32_16x16x32_bf16(a, b, acc[f], 0, 0, 0);
      }
    }
  }

  int rbase = blockIdx.x * 64 + w * 16 + lg * 4;
#pragma unroll
  for (int f = 0; f < 16; f++) {
    int col = f * 16 + l15;
    float bv = bias ? bias[col] : 0.f;
#pragma unroll
    for (int r = 0; r < 4; r++) {
      int row = rbase + r;
      if (row < M) C[(size_t)row * 256 + col] = f2bf(acc[f][r] + bv);
    }
  }
}

// Per-edge MFMA kernel over target-sorted edges: 64 edges per 256-thread block.
// All 16 gather loads hoisted into registers before the silu+MFMA loop.
#define MSG_LD 136   // 128 + 8 bf16 pad (row = 272 B = 68 floats)
__global__ __launch_bounds__(256, 4) void edge_mfma(
    const unsigned short* __restrict__ A, const unsigned short* __restrict__ B,
    const float* __restrict__ w1c,
    const unsigned short* __restrict__ Wm2T, const float* __restrict__ bm2,
    const unsigned short* __restrict__ Wc1T, const float* __restrict__ bc1,
    const float* __restrict__ Wc2, const float* __restrict__ bc2,
    const float* __restrict__ pos_src, const float* __restrict__ pos_tgt,
    const int* __restrict__ esrc, const int* __restrict__ etgt,
    const int* __restrict__ perm,
    float* __restrict__ agg, float* __restrict__ vel, int E)
{
  __shared__ int ss[64], ts[64], segs[64], segtgt[64];
  __shared__ int nsegS;
  __shared__ float rels[64][4];
  __shared__ float velP[64][3];
  __shared__ float w1cS[256];
  __shared__ unsigned short msgs[64 * MSG_LD];  // phase3 aliases rows as c1 f32 (ld 68)

  int tid = threadIdx.x;
  int e0 = blockIdx.x * 64;

  w1cS[tid] = w1c[tid];
  if (tid < 64) {  // exactly wave 0
    int e = e0 + tid;
    int s = 0, t = -1;
    if (e < E) { int eid = perm[e]; s = esrc[eid]; t = etgt[eid]; }
    ss[tid] = s; ts[tid] = t;
    int tc = t < 0 ? 0 : t;
    float rx = pos_tgt[(size_t)tc * 3 + 0] - pos_src[(size_t)s * 3 + 0];
    float ry = pos_tgt[(size_t)tc * 3 + 1] - pos_src[(size_t)s * 3 + 1];
    float rz = pos_tgt[(size_t)tc * 3 + 2] - pos_src[(size_t)s * 3 + 2];
    rels[tid][0] = rx; rels[tid][1] = ry; rels[tid][2] = rz;
    rels[tid][3] = rx * rx + ry * ry + rz * rz;
    velP[tid][0] = 0.f; velP[tid][1] = 0.f; velP[tid][2] = 0.f;
    // segment ids over sorted targets (wave-0 ballot)
    int tprev = __shfl_up(t, 1);
    int flag = (tid > 0 && t != tprev) ? 1 : 0;
    unsigned long long mask = __ballot(flag);
    int segid = (int)__popcll(mask & ((1ULL << tid) - 1ULL)) + flag;
    segs[tid] = segid;
    if (flag || tid == 0) segtgt[segid] = t;
    if (tid == 0) nsegS = (int)__popcll(mask) + 1;
  }
  __syncthreads();

  int w = tid >> 6, lane = tid & 63;
  int l15 = lane & 15, lg = lane >> 4;
  int R0 = w * 16;

  // ---- fused phase 1+2 ----
  int hrow = R0 + l15;                       // this lane's hidden-layer row
  int s_n = ss[hrow];
  int t_n = ts[hrow] < 0 ? 0 : ts[hrow];
  float sq = rels[hrow][3];
  const unsigned short* Arow = &A[(size_t)s_n * 256];
  const unsigned short* Brow = &B[(size_t)t_n * 256];

  // hoist all gathers: 16 x 16B loads issue back-to-back
  bf16x8 av[8], bv[8];
#pragma unroll
  for (int ks = 0; ks < 8; ks++) {
    int c0 = ks * 32 + lg * 8;
    av[ks] = *(const bf16x8*)&Arow[c0];
    bv[ks] = *(const bf16x8*)&Brow[c0];
  }

  f32x4 acc[8];
#pragma unroll
  for (int f = 0; f < 8; f++) acc[f] = (f32x4){0.f, 0.f, 0.f, 0.f};

#pragma unroll
  for (int ks = 0; ks < 8; ks++) {
    int c0 = ks * 32 + lg * 8;
    bf16x8 a;
#pragma unroll
    for (int j = 0; j < 8; j++) {
      float h = silu_f(bfs2f((unsigned short)av[ks][j]) + bfs2f((unsigned short)bv[ks][j])
                       + sq * w1cS[c0 + j]);
      a[j] = (short)f2bf(h);
    }
#pragma unroll
    for (int f = 0; f < 8; f++) {
      bf16x8 b = *(const bf16x8*)&Wm2T[(f * 16 + l15) * 256 + c0];
      acc[f] = __builtin_amdgcn_mfma_f32_16x16x32_bf16(a, b, acc[f], 0, 0, 0);
    }
  }

  // epilogue: silu+bias -> msgs (bf16, LDS) + run-length merged global agg atomics
#pragma unroll
  for (int f = 0; f < 8; f++) {
    int col = f * 16 + l15;
    float bias = bm2[col];
    int curseg = -1; float runv = 0.f;
#pragma unroll
    for (int r = 0; r < 4; r++) {
      int row = R0 + lg * 4 + r;
      float v = silu_f(acc[f][r] + bias);
      msgs[row * MSG_LD + col] = f2bf(v);
      int sg = (e0 + row < E) ? segs[row] : -1;
      if (sg != curseg) {
        if (curseg >= 0)
          atomicAdd(&agg[(size_t)segtgt[curseg] * 128 + col], runv);
        curseg = sg; runv = 0.f;
      }
      if (sg >= 0) runv += v;
    }
    if (curseg >= 0)
      atomicAdd(&agg[(size_t)segtgt[curseg] * 128 + col], runv);
  }
  __syncthreads();

  // phase 3: c1(64x64) = silu(msg(64x128) @ Wc1(128x64) + bc1), MFMA
  f32x4 acc2[4];
#pragma unroll
  for (int f = 0; f < 4; f++) acc2[f] = (f32x4){0.f, 0.f, 0.f, 0.f};
  {
    const unsigned short* mrow = &msgs[hrow * MSG_LD];
#pragma unroll
    for (int ks = 0; ks < 4; ks++) {
      int kb = ks * 32 + lg * 8;
      bf16x8 a = *(const bf16x8*)&mrow[kb];
#pragma unroll
      for (int f = 0; f < 4; f++) {
        bf16x8 b = *(const bf16x8*)&Wc1T[(f * 16 + l15) * 128 + kb];
        acc2[f] = __builtin_amdgcn_mfma_f32_16x16x32_bf16(a, b, acc2[f], 0, 0, 0);
      }
    }
  }
  // c1 aliases msgs row-for-row (272 B = 68 floats per row)
  float* c1 = (float*)msgs;
#pragma unroll
  for (int f = 0; f < 4; f++) {
    int col = f * 16 + l15;
    float bias = bc1[col];
#pragma unroll
    for (int r = 0; r < 4; r++) {
      int row = R0 + lg * 4 + r;
      c1[row * 68 + col] = silu_f(acc2[f][r] + bias);
    }
  }
  __syncthreads();

  // phase 4: wgt = tanh(c1 @ Wc2 + bc2); velP[seg] += wgt * rel
  {
    int row = tid >> 2, sub = tid & 3;
    const float* crow = &c1[row * 68 + sub * 16];
    float dot = 0.f;
#pragma unroll
    for (int k = 0; k < 16; k++) dot = fmaf(crow[k], Wc2[sub * 16 + k], dot);
    dot += __shfl_xor(dot, 1);
    dot += __shfl_xor(dot, 2);
    if (sub == 0 && e0 + row < E) {
      float wv = tanhf(dot + bc2[0]);
      int sg = segs[row];
      atomicAdd(&velP[sg][0], wv * rels[row][0]);
      atomicAdd(&velP[sg][1], wv * rels[row][1]);
      atomicAdd(&velP[sg][2], wv * rels[row][2]);
    }
  }
  __syncthreads();
  int nseg = nsegS;
  if (tid < 3 * nseg) {
    int s = tid / 3, k = tid - 3 * s;
    int t = segtgt[s];
    if (t >= 0) atomicAdd(&vel[(size_t)t * 3 + k], velP[s][k]);
  }
}

// Per-target update MLP + layernorm. 32 targets per 256-thread block.
__global__ __launch_bounds__(256, 2) void tgt_update(
    const float* __restrict__ h_tgt, const float* __restrict__ agg,
    const float* __restrict__ Wu1, const float* __restrict__ bu1,
    const float* __restrict__ Wu2, const float* __restrict__ bu2,
    const float* __restrict__ gamma, const float* __restrict__ beta,
    float* __restrict__ out, int M)
{
  __shared__ float ht[32][132];
  __shared__ float xs[32][132];
  int row0 = blockIdx.x * 32;
  int tid = threadIdx.x;

  for (int i = tid; i < 32 * 32; i += 256) {
    int r = i >> 5, q = i & 31;
    int row = row0 + r;
    float4 a = make_float4(0.f, 0.f, 0.f, 0.f), g = a;
    if (row < M) {
      a = ((const float4*)(h_tgt + (size_t)row * 128))[q];
      g = ((const float4*)(agg + (size_t)row * 128))[q];
    }
    ((float4*)&ht[r][0])[q] = a;
    ((float4*)&xs[r][0])[q] = g;
  }
  __syncthreads();

  int j = tid & 127;
  int rg = tid >> 7;
  float acc[16];
  {
    float b = bu1[j];
#pragma unroll
    for (int r = 0; r < 16; r++) acc[r] = b;
  }
  for (int k = 0; k < 128; k += 4) {
    float w0 = Wu1[(size_t)(k + 0) * 128 + j];
    float w1 = Wu1[(size_t)(k + 1) * 128 + j];
    float w2 = Wu1[(size_t)(k + 2) * 128 + j];
    float w3 = Wu1[(size_t)(k + 3) * 128 + j];
#pragma unroll
    for (int r = 0; r < 16; r++) {
      float4 x = *(const float4*)&ht[rg * 16 + r][k];
      acc[r] = fmaf(x.x, w0, fmaf(x.y, w1, fmaf(x.z, w2, fmaf(x.w, w3, acc[r]))));
    }
  }
  for (int k = 0; k < 128; k += 4) {
    float w0 = Wu1[(size_t)(128 + k + 0) * 128 + j];
    float w1 = Wu1[(size_t)(128 + k + 1) * 128 + j];
    float w2 = Wu1[(size_t)(128 + k + 2) * 128 + j];
    float w3 = Wu1[(size_t)(128 + k + 3) * 128 + j];
#pragma unroll
    for (int r = 0; r < 16; r++) {
      float4 x = *(const float4*)&xs[rg * 16 + r][k];
      acc[r] = fmaf(x.x, w0, fmaf(x.y, w1, fmaf(x.z, w2, fmaf(x.w, w3, acc[r]))));
    }
  }
#pragma unroll
  for (int r = 0; r < 16; r++) acc[r] = silu_f(acc[r]);
  __syncthreads();
#pragma unroll
  for (int r = 0; r < 16; r++) xs[rg * 16 + r][j] = acc[r];
  __syncthreads();

  float acc2[16];
  {
    float b = bu2[j];
#pragma unroll
    for (int r = 0; r < 16; r++) acc2[r] = b;
  }
  for (int k = 0; k < 128; k += 4) {
    float w0 = Wu2[(size_t)(k + 0) * 128 + j];
    float w1 = Wu2[(size_t)(k + 1) * 128 + j];
    float w2 = Wu2[(size_t)(k + 2) * 128 + j];
    float w3 = Wu2[(size_t)(k + 3) * 128 + j];
#pragma unroll
    for (int r = 0; r < 16; r++) {
      float4 x = *(const float4*)&xs[rg * 16 + r][k];
      acc2[r] = fmaf(x.x, w0, fmaf(x.y, w1, fmaf(x.z, w2, fmaf(x.w, w3, acc2[r]))));
    }
  }
  __syncthreads();
#pragma unroll
  for (int r = 0; r < 16; r++) xs[rg * 16 + r][j] = acc2[r] + ht[rg * 16 + r][j];
  __syncthreads();

  int row = tid >> 3, sub = tid & 7;
  float s = 0.f, s2 = 0.f;
#pragma unroll
  for (int q = 0; q < 16; q++) {
    float v = xs[row][sub * 16 + q];
    s += v; s2 += v * v;
  }
  for (int off = 1; off < 8; off <<= 1) {
    s += __shfl_xor(s, off, 64);
    s2 += __shfl_xor(s2, off, 64);
  }
  float mu = s * (1.f / 128.f);
  float var = s2 * (1.f / 128.f) - mu * mu;
  float rs = rsqrtf(var + 1e-5f);
  int orow = row0 + row;
  if (orow < M) {
#pragma unroll
    for (int q = 0; q < 16; q++) {
      int c = sub * 16 + q;
      out[(size_t)orow * 128 + c] = (xs[row][c] - mu) * rs * gamma[c] + beta[c];
    }
  }
}

extern "C" void kernel_launch(void* const* d_in, const int* in_sizes, int n_in,
                              void* d_out, int out_size, void* d_ws, size_t ws_size,
                              hipStream_t stream) {
  const float* h_src  = (const float*)d_in[0];
  const float* h_tgt  = (const float*)d_in[1];
  const float* pos_src = (const float*)d_in[2];
  const float* pos_tgt = (const float*)d_in[3];
  const float* t_emb  = (const float*)d_in[4];
  const float* W_m1 = (const float*)d_in[5];
  const float* b_m1 = (const float*)d_in[6];
  const float* W_m2 = (const float*)d_in[7];
  const float* b_m2 = (const float*)d_in[8];
  const float* W_c1 = (const float*)d_in[9];
  const float* b_c1 = (const float*)d_in[10];
  const float* W_c2 = (const float*)d_in[11];
  const float* b_c2 = (const float*)d_in[12];
  const float* W_u1 = (const float*)d_in[13];
  const float* b_u1 = (const float*)d_in[14];
  const float* W_u2 = (const float*)d_in[15];
  const float* b_u2 = (const float*)d_in[16];
  const float* gamma = (const float*)d_in[17];
  const float* beta  = (const float*)d_in[18];
  const int* esrc = (const int*)d_in[19];
  const int* etgt = (const int*)d_in[20];

  int n_src = in_sizes[0] / 128;
  int n_tgt = in_sizes[1] / 128;
  int E = in_sizes[19];

  // workspace layout
  unsigned short* A    = (unsigned short*)d_ws;                 // n_src*256 bf16
  unsigned short* B    = A + (size_t)n_src * 256;               // n_tgt*256 bf16
  unsigned short* Wm2T = B + (size_t)n_tgt * 256;               // 128*256 bf16
  unsigned short* Wc1T = Wm2T + 128 * 256;                      // 64*128 bf16
  unsigned short* W1aT = Wc1T + 64 * 128;                       // 256*128 bf16
  unsigned short* W1bT = W1aT + 256 * 128;                      // 256*128 bf16
  unsigned short* W1dT = W1bT + 256 * 128;                      // 256*128 bf16
  float* agg  = (float*)(W1dT + 256 * 128);                     // n_tgt*128 f32
  int* cnt    = (int*)(agg + (size_t)n_tgt * 128);              // n_tgt
  int* cursor = cnt + n_tgt;                                    // n_tgt
  int* perm   = cursor + n_tgt;                                 // E
  float* out_h = (float*)d_out;                                 // n_tgt x 128
  float* vel = out_h + (size_t)n_tgt * 128;                     // n_tgt x 3

  hipMemsetAsync(agg, 0, (size_t)n_tgt * 128 * sizeof(float), stream);
  hipMemsetAsync(vel, 0, (size_t)n_tgt * 3 * sizeof(float), stream);
  hipMemsetAsync(cnt, 0, (size_t)n_tgt * sizeof(int), stream);

  dim3 blk(256);
  prep_weights<<<128, blk, 0, stream>>>(W_m2, W_c1, W_m1, Wm2T, Wc1T, W1aT, W1bT, W1dT);
  count_edges<<<(E + 255) / 256, blk, 0, stream>>>(etgt, cnt, E);
  scan_bins<<<1, blk, 0, stream>>>(cnt, cursor, n_tgt);
  scatter_edges<<<(E + 255) / 256, blk, 0, stream>>>(etgt, cursor, perm, E);
  node_mfma<<<(n_src + 63) / 64, blk, 0, stream>>>(
      h_src, W1aT, nullptr, nullptr, nullptr, A, n_src);
  node_mfma<<<(n_tgt + 63) / 64, blk, 0, stream>>>(
      h_tgt, W1bT, t_emb, W1dT, b_m1, B, n_tgt);
  edge_mfma<<<(E + 63) / 64, blk, 0, stream>>>(
      A, B, W_m1 + 256 * 256, Wm2T, b_m2, Wc1T, b_c1, W_c2, b_c2,
      pos_src, pos_tgt, esrc, etgt, perm, agg, vel, E);
  tgt_update<<<(n_tgt + 31) / 32, blk, 0, stream>>>(
      h_tgt, agg, W_u1, b_u1, W_u2, b_u2, gamma, beta, out_h, n_tgt);
}

// Round 12
// 1093.000 us; speedup vs baseline: 1.3135x; 1.0806x over previous
//
#include <hip/hip_runtime.h>

typedef __attribute__((ext_vector_type(8))) short bf16x8;
typedef __attribute__((ext_vector_type(4))) float f32x4;

__device__ __forceinline__ float silu_f(float x) {
  return x / (1.0f + __expf(-x));
}

__device__ __forceinline__ unsigned short f2bf(float f) {
  union { float f; unsigned int u; } x; x.f = f;
  unsigned int u = x.u + 0x7fffu + ((x.u >> 16) & 1u);  // RNE
  return (unsigned short)(u >> 16);
}

__device__ __forceinline__ float bfs2f(unsigned short s) {
  return __uint_as_float((unsigned int)s << 16);
}

// Transpose+convert all weights to bf16 [n][k] layouts for MFMA B-operands.
__global__ void prep_weights(const float* __restrict__ Wm2, const float* __restrict__ Wc1,
                             const float* __restrict__ Wm1,
                             unsigned short* __restrict__ Wm2T, unsigned short* __restrict__ Wc1T,
                             unsigned short* __restrict__ W1aT, unsigned short* __restrict__ W1bT,
                             unsigned short* __restrict__ W1dT)
{
  int i = blockIdx.x * 256 + threadIdx.x;   // grid covers 32768
  if (i < 128 * 256) {
    int n = i >> 8, k = i & 255;
    Wm2T[i] = f2bf(Wm2[k * 128 + n]);
  }
  if (i < 64 * 128) {
    int n = i >> 7, k = i & 127;
    Wc1T[i] = f2bf(Wc1[k * 64 + n]);
  }
  if (i < 256 * 128) {
    int n = i >> 7, k = i & 127;
    W1aT[i] = f2bf(Wm1[(size_t)k * 256 + n]);
    W1bT[i] = f2bf(Wm1[(size_t)(128 + k) * 256 + n]);
    W1dT[i] = f2bf(Wm1[(size_t)(257 + k) * 256 + n]);
  }
}

// ---- counting sort of edges by target ----
__global__ void count_edges(const int* __restrict__ etgt, int* __restrict__ cnt, int E) {
  int e = blockIdx.x * 256 + threadIdx.x;
  if (e < E) atomicAdd(&cnt[etgt[e]], 1);
}

__global__ void scan_bins(const int* __restrict__ cnt, int* __restrict__ cursor, int n) {
  __shared__ int sums[256];
  int tid = threadIdx.x;
  int chunk = (n + 255) >> 8;
  int lo = tid * chunk, hi = min(lo + chunk, n);
  int s = 0;
  for (int i = lo; i < hi; i++) s += cnt[i];
  sums[tid] = s;
  __syncthreads();
  if (tid == 0) {
    int acc = 0;
    for (int i = 0; i < 256; i++) { int t = sums[i]; sums[i] = acc; acc += t; }
  }
  __syncthreads();
  int run = sums[tid];
  for (int i = lo; i < hi; i++) { int c = cnt[i]; cursor[i] = run; run += c; }
}

__global__ void scatter_edges(const int* __restrict__ etgt, int* __restrict__ cursor,
                              int* __restrict__ perm, int E) {
  int e = blockIdx.x * 256 + threadIdx.x;
  if (e < E) {
    int p = atomicAdd(&cursor[etgt[e]], 1);
    perm[p] = e;
  }
}

// MFMA node table builder: C[M x 256] bf16 = X1@W1T^T [+ X2@W2T^T] [+ bias].
__global__ __launch_bounds__(256, 4) void node_mfma(
    const float* __restrict__ X1, const unsigned short* __restrict__ W1T,
    const float* __restrict__ X2, const unsigned short* __restrict__ W2T,
    const float* __restrict__ bias, unsigned short* __restrict__ C, int M)
{
  int tid = threadIdx.x;
  int w = tid >> 6, lane = tid & 63;
  int l15 = lane & 15, lg = lane >> 4;
  int grow = blockIdx.x * 64 + w * 16 + l15;   // this lane's input row
  int rowc = grow < M ? grow : 0;

  f32x4 acc[16];
#pragma unroll
  for (int f = 0; f < 16; f++) acc[f] = (f32x4){0.f, 0.f, 0.f, 0.f};

  for (int pass = 0; pass < 2; ++pass) {
    const float* X = pass ? X2 : X1;
    const unsigned short* WT = pass ? W2T : W1T;
    if (X == nullptr) break;
    const float* Xrow = X + (size_t)rowc * 128;
#pragma unroll
    for (int ks = 0; ks < 4; ks++) {
      int c0 = ks * 32 + lg * 8;
      float4 x0 = *(const float4*)&Xrow[c0];
      float4 x1 = *(const float4*)&Xrow[c0 + 4];
      bf16x8 a;
      a[0] = (short)f2bf(x0.x); a[1] = (short)f2bf(x0.y);
      a[2] = (short)f2bf(x0.z); a[3] = (short)f2bf(x0.w);
      a[4] = (short)f2bf(x1.x); a[5] = (short)f2bf(x1.y);
      a[6] = (short)f2bf(x1.z); a[7] = (short)f2bf(x1.w);
#pragma unroll
      for (int f = 0; f < 16; f++) {
        bf16x8 b = *(const bf16x8*)&WT[(size_t)(f * 16 + l15) * 128 + c0];
        acc[f] = __builtin_amdgcn_mfma_f32_16x16x32_bf16(a, b, acc[f], 0, 0, 0);
      }
    }
  }

  int rbase = blockIdx.x * 64 + w * 16 + lg * 4;
#pragma unroll
  for (int f = 0; f < 16; f++) {
    int col = f * 16 + l15;
    float bv = bias ? bias[col] : 0.f;
#pragma unroll
    for (int r = 0; r < 4; r++) {
      int row = rbase + r;
      if (row < M) C[(size_t)row * 256 + col] = f2bf(acc[f][r] + bv);
    }
  }
}

// Per-edge MFMA kernel over target-sorted edges: 64 edges per 256-thread block.
// agg reduction: per-block LDS segment-sum over the msgs tile -> ONE global
// atomic per (segment, col) ~ 8M total (under the ~50 G/s atomic ceiling).
#define MSG_LD 136   // 128 + 8 bf16 pad (row = 272 B = 68 floats)
__global__ __launch_bounds__(256, 4) void edge_mfma(
    const unsigned short* __restrict__ A, const unsigned short* __restrict__ B,
    const float* __restrict__ w1c,
    const unsigned short* __restrict__ Wm2T, const float* __restrict__ bm2,
    const unsigned short* __restrict__ Wc1T, const float* __restrict__ bc1,
    const float* __restrict__ Wc2, const float* __restrict__ bc2,
    const float* __restrict__ pos_src, const float* __restrict__ pos_tgt,
    const int* __restrict__ esrc, const int* __restrict__ etgt,
    const int* __restrict__ perm,
    float* __restrict__ agg, float* __restrict__ vel, int E)
{
  __shared__ int ss[64], ts[64], segs[64], segtgt[66], segstart[66];
  __shared__ int nsegS;
  __shared__ float rels[64][4];
  __shared__ float velP[64][3];
  __shared__ float w1cS[256];
  __shared__ unsigned short msgs[64 * MSG_LD];  // phase3 aliases rows as c1 f32 (ld 68)

  int tid = threadIdx.x;
  int e0 = blockIdx.x * 64;

  w1cS[tid] = w1c[tid];
  if (tid < 64) {  // exactly wave 0
    int e = e0 + tid;
    int s = 0, t = -1;
    if (e < E) { int eid = perm[e]; s = esrc[eid]; t = etgt[eid]; }
    ss[tid] = s; ts[tid] = t;
    int tc = t < 0 ? 0 : t;
    float rx = pos_tgt[(size_t)tc * 3 + 0] - pos_src[(size_t)s * 3 + 0];
    float ry = pos_tgt[(size_t)tc * 3 + 1] - pos_src[(size_t)s * 3 + 1];
    float rz = pos_tgt[(size_t)tc * 3 + 2] - pos_src[(size_t)s * 3 + 2];
    rels[tid][0] = rx; rels[tid][1] = ry; rels[tid][2] = rz;
    rels[tid][3] = rx * rx + ry * ry + rz * rz;
    velP[tid][0] = 0.f; velP[tid][1] = 0.f; velP[tid][2] = 0.f;
    // segment ids over sorted targets (wave-0 ballot)
    int tprev = __shfl_up(t, 1);
    int flag = (tid > 0 && t != tprev) ? 1 : 0;
    unsigned long long mask = __ballot(flag);
    int segid = (int)__popcll(mask & ((1ULL << tid) - 1ULL)) + flag;
    segs[tid] = segid;
    if (flag || tid == 0) { segtgt[segid] = t; segstart[segid] = tid; }
    if (tid == 0) {
      int n = (int)__popcll(mask) + 1;
      nsegS = n;
      segtgt[n] = -1;
      segstart[n] = 64;
    }
  }
  __syncthreads();

  int w = tid >> 6, lane = tid & 63;
  int l15 = lane & 15, lg = lane >> 4;
  int R0 = w * 16;

  // ---- fused phase 1+2 ----
  int hrow = R0 + l15;                       // this lane's hidden-layer row
  int s_n = ss[hrow];
  int t_n = ts[hrow] < 0 ? 0 : ts[hrow];
  float sq = rels[hrow][3];
  const unsigned short* Arow = &A[(size_t)s_n * 256];
  const unsigned short* Brow = &B[(size_t)t_n * 256];

  bf16x8 av[8], bv[8];
#pragma unroll
  for (int ks = 0; ks < 8; ks++) {
    int c0 = ks * 32 + lg * 8;
    av[ks] = *(const bf16x8*)&Arow[c0];
    bv[ks] = *(const bf16x8*)&Brow[c0];
  }

  f32x4 acc[8];
#pragma unroll
  for (int f = 0; f < 8; f++) acc[f] = (f32x4){0.f, 0.f, 0.f, 0.f};

#pragma unroll
  for (int ks = 0; ks < 8; ks++) {
    int c0 = ks * 32 + lg * 8;
    bf16x8 a;
#pragma unroll
    for (int j = 0; j < 8; j++) {
      float h = silu_f(bfs2f((unsigned short)av[ks][j]) + bfs2f((unsigned short)bv[ks][j])
                       + sq * w1cS[c0 + j]);
      a[j] = (short)f2bf(h);
    }
#pragma unroll
    for (int f = 0; f < 8; f++) {
      bf16x8 b = *(const bf16x8*)&Wm2T[(f * 16 + l15) * 256 + c0];
      acc[f] = __builtin_amdgcn_mfma_f32_16x16x32_bf16(a, b, acc[f], 0, 0, 0);
    }
  }

  // epilogue: silu+bias -> msgs (bf16, LDS). No global atomics here.
#pragma unroll
  for (int f = 0; f < 8; f++) {
    int col = f * 16 + l15;
    float bias = bm2[col];
#pragma unroll
    for (int r = 0; r < 4; r++) {
      int row = R0 + lg * 4 + r;
      float v = silu_f(acc[f][r] + bias);
      msgs[row * MSG_LD + col] = f2bf(v);
    }
  }
  __syncthreads();

  // agg: per-block LDS segment-sum -> one global atomic per (seg, col).
  int nseg = nsegS;
  {
    int col = tid & 127;
    for (int s = tid >> 7; s < nseg; s += 2) {
      int t = segtgt[s];
      if (t < 0) continue;
      int r0 = segstart[s], r1 = segstart[s + 1];
      float sum = 0.f;
      for (int r = r0; r < r1; r++) sum += bfs2f(msgs[r * MSG_LD + col]);
      atomicAdd(&agg[(size_t)t * 128 + col], sum);
    }
  }
  __syncthreads();  // segment-sum reads done before c1 aliases msgs

  // phase 3: c1(64x64) = silu(msg(64x128) @ Wc1(128x64) + bc1), MFMA
  f32x4 acc2[4];
#pragma unroll
  for (int f = 0; f < 4; f++) acc2[f] = (f32x4){0.f, 0.f, 0.f, 0.f};
  {
    const unsigned short* mrow = &msgs[hrow * MSG_LD];
#pragma unroll
    for (int ks = 0; ks < 4; ks++) {
      int kb = ks * 32 + lg * 8;
      bf16x8 a = *(const bf16x8*)&mrow[kb];
#pragma unroll
      for (int f = 0; f < 4; f++) {
        bf16x8 b = *(const bf16x8*)&Wc1T[(f * 16 + l15) * 128 + kb];
        acc2[f] = __builtin_amdgcn_mfma_f32_16x16x32_bf16(a, b, acc2[f], 0, 0, 0);
      }
    }
  }
  // c1 aliases msgs row-for-row (272 B = 68 floats per row); this wave's msgs
  // reads precede its c1 writes, and waves touch disjoint row ranges.
  float* c1 = (float*)msgs;
#pragma unroll
  for (int f = 0; f < 4; f++) {
    int col = f * 16 + l15;
    float bias = bc1[col];
#pragma unroll
    for (int r = 0; r < 4; r++) {
      int row = R0 + lg * 4 + r;
      c1[row * 68 + col] = silu_f(acc2[f][r] + bias);
    }
  }
  __syncthreads();

  // phase 4: wgt = tanh(c1 @ Wc2 + bc2); velP[seg] += wgt * rel
  {
    int row = tid >> 2, sub = tid & 3;
    const float* crow = &c1[row * 68 + sub * 16];
    float dot = 0.f;
#pragma unroll
    for (int k = 0; k < 16; k++) dot = fmaf(crow[k], Wc2[sub * 16 + k], dot);
    dot += __shfl_xor(dot, 1);
    dot += __shfl_xor(dot, 2);
    if (sub == 0 && e0 + row < E) {
      float wv = tanhf(dot + bc2[0]);
      int sg = segs[row];
      atomicAdd(&velP[sg][0], wv * rels[row][0]);
      atomicAdd(&velP[sg][1], wv * rels[row][1]);
      atomicAdd(&velP[sg][2], wv * rels[row][2]);
    }
  }
  __syncthreads();
  if (tid < 3 * nseg) {
    int s = tid / 3, k = tid - 3 * s;
    int t = segtgt[s];
    if (t >= 0) atomicAdd(&vel[(size_t)t * 3 + k], velP[s][k]);
  }
}

// Per-target update MLP + layernorm. 32 targets per 256-thread block.
__global__ __launch_bounds__(256, 2) void tgt_update(
    const float* __restrict__ h_tgt, const float* __restrict__ agg,
    const float* __restrict__ Wu1, const float* __restrict__ bu1,
    const float* __restrict__ Wu2, const float* __restrict__ bu2,
    const float* __restrict__ gamma, const float* __restrict__ beta,
    float* __restrict__ out, int M)
{
  __shared__ float ht[32][132];
  __shared__ float xs[32][132];
  int row0 = blockIdx.x * 32;
  int tid = threadIdx.x;

  for (int i = tid; i < 32 * 32; i += 256) {
    int r = i >> 5, q = i & 31;
    int row = row0 + r;
    float4 a = make_float4(0.f, 0.f, 0.f, 0.f), g = a;
    if (row < M) {
      a = ((const float4*)(h_tgt + (size_t)row * 128))[q];
      g = ((const float4*)(agg + (size_t)row * 128))[q];
    }
    ((float4*)&ht[r][0])[q] = a;
    ((float4*)&xs[r][0])[q] = g;
  }
  __syncthreads();

  int j = tid & 127;
  int rg = tid >> 7;
  float acc[16];
  {
    float b = bu1[j];
#pragma unroll
    for (int r = 0; r < 16; r++) acc[r] = b;
  }
  for (int k = 0; k < 128; k += 4) {
    float w0 = Wu1[(size_t)(k + 0) * 128 + j];
    float w1 = Wu1[(size_t)(k + 1) * 128 + j];
    float w2 = Wu1[(size_t)(k + 2) * 128 + j];
    float w3 = Wu1[(size_t)(k + 3) * 128 + j];
#pragma unroll
    for (int r = 0; r < 16; r++) {
      float4 x = *(const float4*)&ht[rg * 16 + r][k];
      acc[r] = fmaf(x.x, w0, fmaf(x.y, w1, fmaf(x.z, w2, fmaf(x.w, w3, acc[r]))));
    }
  }
  for (int k = 0; k < 128; k += 4) {
    float w0 = Wu1[(size_t)(128 + k + 0) * 128 + j];
    float w1 = Wu1[(size_t)(128 + k + 1) * 128 + j];
    float w2 = Wu1[(size_t)(128 + k + 2) * 128 + j];
    float w3 = Wu1[(size_t)(128 + k + 3) * 128 + j];
#pragma unroll
    for (int r = 0; r < 16; r++) {
      float4 x = *(const float4*)&xs[rg * 16 + r][k];
      acc[r] = fmaf(x.x, w0, fmaf(x.y, w1, fmaf(x.z, w2, fmaf(x.w, w3, acc[r]))));
    }
  }
#pragma unroll
  for (int r = 0; r < 16; r++) acc[r] = silu_f(acc[r]);
  __syncthreads();
#pragma unroll
  for (int r = 0; r < 16; r++) xs[rg * 16 + r][j] = acc[r];
  __syncthreads();

  float acc2[16];
  {
    float b = bu2[j];
#pragma unroll
    for (int r = 0; r < 16; r++) acc2[r] = b;
  }
  for (int k = 0; k < 128; k += 4) {
    float w0 = Wu2[(size_t)(k + 0) * 128 + j];
    float w1 = Wu2[(size_t)(k + 1) * 128 + j];
    float w2 = Wu2[(size_t)(k + 2) * 128 + j];
    float w3 = Wu2[(size_t)(k + 3) * 128 + j];
#pragma unroll
    for (int r = 0; r < 16; r++) {
      float4 x = *(const float4*)&xs[rg * 16 + r][k];
      acc2[r] = fmaf(x.x, w0, fmaf(x.y, w1, fmaf(x.z, w2, fmaf(x.w, w3, acc2[r]))));
    }
  }
  __syncthreads();
#pragma unroll
  for (int r = 0; r < 16; r++) xs[rg * 16 + r][j] = acc2[r] + ht[rg * 16 + r][j];
  __syncthreads();

  int row = tid >> 3, sub = tid & 7;
  float s = 0.f, s2 = 0.f;
#pragma unroll
  for (int q = 0; q < 16; q++) {
    float v = xs[row][sub * 16 + q];
    s += v; s2 += v * v;
  }
  for (int off = 1; off < 8; off <<= 1) {
    s += __shfl_xor(s, off, 64);
    s2 += __shfl_xor(s2, off, 64);
  }
  float mu = s * (1.f / 128.f);
  float var = s2 * (1.f / 128.f) - mu * mu;
  float rs = rsqrtf(var + 1e-5f);
  int orow = row0 + row;
  if (orow < M) {
#pragma unroll
    for (int q = 0; q < 16; q++) {
      int c = sub * 16 + q;
      out[(size_t)orow * 128 + c] = (xs[row][c] - mu) * rs * gamma[c] + beta[c];
    }
  }
}

extern "C" void kernel_launch(void* const* d_in, const int* in_sizes, int n_in,
                              void* d_out, int out_size, void* d_ws, size_t ws_size,
                              hipStream_t stream) {
  const float* h_src  = (const float*)d_in[0];
  const float* h_tgt  = (const float*)d_in[1];
  const float* pos_src = (const float*)d_in[2];
  const float* pos_tgt = (const float*)d_in[3];
  const float* t_emb  = (const float*)d_in[4];
  const float* W_m1 = (const float*)d_in[5];
  const float* b_m1 = (const float*)d_in[6];
  const float* W_m2 = (const float*)d_in[7];
  const float* b_m2 = (const float*)d_in[8];
  const float* W_c1 = (const float*)d_in[9];
  const float* b_c1 = (const float*)d_in[10];
  const float* W_c2 = (const float*)d_in[11];
  const float* b_c2 = (const float*)d_in[12];
  const float* W_u1 = (const float*)d_in[13];
  const float* b_u1 = (const float*)d_in[14];
  const float* W_u2 = (const float*)d_in[15];
  const float* b_u2 = (const float*)d_in[16];
  const float* gamma = (const float*)d_in[17];
  const float* beta  = (const float*)d_in[18];
  const int* esrc = (const int*)d_in[19];
  const int* etgt = (const int*)d_in[20];

  int n_src = in_sizes[0] / 128;
  int n_tgt = in_sizes[1] / 128;
  int E = in_sizes[19];

  // workspace layout
  unsigned short* A    = (unsigned short*)d_ws;                 // n_src*256 bf16
  unsigned short* B    = A + (size_t)n_src * 256;               // n_tgt*256 bf16
  unsigned short* Wm2T = B + (size_t)n_tgt * 256;               // 128*256 bf16
  unsigned short* Wc1T = Wm2T + 128 * 256;                      // 64*128 bf16
  unsigned short* W1aT = Wc1T + 64 * 128;                       // 256*128 bf16
  unsigned short* W1bT = W1aT + 256 * 128;                      // 256*128 bf16
  unsigned short* W1dT = W1bT + 256 * 128;                      // 256*128 bf16
  float* agg  = (float*)(W1dT + 256 * 128);                     // n_tgt*128 f32
  int* cnt    = (int*)(agg + (size_t)n_tgt * 128);              // n_tgt
  int* cursor = cnt + n_tgt;                                    // n_tgt
  int* perm   = cursor + n_tgt;                                 // E
  float* out_h = (float*)d_out;                                 // n_tgt x 128
  float* vel = out_h + (size_t)n_tgt * 128;                     // n_tgt x 3

  hipMemsetAsync(agg, 0, (size_t)n_tgt * 128 * sizeof(float), stream);
  hipMemsetAsync(vel, 0, (size_t)n_tgt * 3 * sizeof(float), stream);
  hipMemsetAsync(cnt, 0, (size_t)n_tgt * sizeof(int), stream);

  dim3 blk(256);
  prep_weights<<<128, blk, 0, stream>>>(W_m2, W_c1, W_m1, Wm2T, Wc1T, W1aT, W1bT, W1dT);
  count_edges<<<(E + 255) / 256, blk, 0, stream>>>(etgt, cnt, E);
  scan_bins<<<1, blk, 0, stream>>>(cnt, cursor, n_tgt);
  scatter_edges<<<(E + 255) / 256, blk, 0, stream>>>(etgt, cursor, perm, E);
  node_mfma<<<(n_src + 63) / 64, blk, 0, stream>>>(
      h_src, W1aT, nullptr, nullptr, nullptr, A, n_src);
  node_mfma<<<(n_tgt + 63) / 64, blk, 0, stream>>>(
      h_tgt, W1bT, t_emb, W1dT, b_m1, B, n_tgt);
  edge_mfma<<<(E + 63) / 64, blk, 0, stream>>>(
      A, B, W_m1 + 256 * 256, Wm2T, b_m2, Wc1T, b_c1, W_c2, b_c2,
      pos_src, pos_tgt, esrc, etgt, perm, agg, vel, E);
  tgt_update<<<(n_tgt + 31) / 32, blk, 0, stream>>>(
      h_tgt, agg, W_u1, b_u1, W_u2, b_u2, gamma, beta, out_h, n_tgt);
}

// Round 13
// 1028.297 us; speedup vs baseline: 1.3961x; 1.0629x over previous
//
#include <hip/hip_runtime.h>

typedef __attribute__((ext_vector_type(8))) short bf16x8;
typedef __attribute__((ext_vector_type(4))) float f32x4;

__device__ __forceinline__ float silu_f(float x) {
  return x / (1.0f + __expf(-x));
}

__device__ __forceinline__ unsigned short f2bf(float f) {
  union { float f; unsigned int u; } x; x.f = f;
  unsigned int u = x.u + 0x7fffu + ((x.u >> 16) & 1u);  // RNE
  return (unsigned short)(u >> 16);
}

__device__ __forceinline__ float bfs2f(unsigned short s) {
  return __uint_as_float((unsigned int)s << 16);
}

// Transpose+convert all weights to bf16 [n][k] layouts for MFMA B-operands.
__global__ void prep_weights(const float* __restrict__ Wm2, const float* __restrict__ Wc1,
                             const float* __restrict__ Wm1,
                             const float* __restrict__ Wu1, const float* __restrict__ Wu2,
                             unsigned short* __restrict__ Wm2T, unsigned short* __restrict__ Wc1T,
                             unsigned short* __restrict__ W1aT, unsigned short* __restrict__ W1bT,
                             unsigned short* __restrict__ W1dT,
                             unsigned short* __restrict__ Wu1T, unsigned short* __restrict__ Wu2T)
{
  int i = blockIdx.x * 256 + threadIdx.x;   // grid covers 32768
  if (i < 128 * 256) {
    int n = i >> 8, k = i & 255;
    Wm2T[i] = f2bf(Wm2[k * 128 + n]);
    Wu1T[i] = f2bf(Wu1[(size_t)k * 128 + n]);   // Wu1 is 256x128
  }
  if (i < 64 * 128) {
    int n = i >> 7, k = i & 127;
    Wc1T[i] = f2bf(Wc1[k * 64 + n]);
  }
  if (i < 128 * 128) {
    int n = i >> 7, k = i & 127;
    Wu2T[i] = f2bf(Wu2[k * 128 + n]);
  }
  if (i < 256 * 128) {
    int n = i >> 7, k = i & 127;
    W1aT[i] = f2bf(Wm1[(size_t)k * 256 + n]);
    W1bT[i] = f2bf(Wm1[(size_t)(128 + k) * 256 + n]);
    W1dT[i] = f2bf(Wm1[(size_t)(257 + k) * 256 + n]);
  }
}

// ---- counting sort of edges by target ----
__global__ void count_edges(const int* __restrict__ etgt, int* __restrict__ cnt, int E) {
  int e = blockIdx.x * 256 + threadIdx.x;
  if (e < E) atomicAdd(&cnt[etgt[e]], 1);
}

__global__ void scan_bins(const int* __restrict__ cnt, int* __restrict__ cursor, int n) {
  __shared__ int sums[256];
  int tid = threadIdx.x;
  int chunk = (n + 255) >> 8;
  int lo = tid * chunk, hi = min(lo + chunk, n);
  int s = 0;
  for (int i = lo; i < hi; i++) s += cnt[i];
  sums[tid] = s;
  __syncthreads();
  if (tid == 0) {
    int acc = 0;
    for (int i = 0; i < 256; i++) { int t = sums[i]; sums[i] = acc; acc += t; }
  }
  __syncthreads();
  int run = sums[tid];
  for (int i = lo; i < hi; i++) { int c = cnt[i]; cursor[i] = run; run += c; }
}

__global__ void scatter_edges(const int* __restrict__ etgt, int* __restrict__ cursor,
                              int* __restrict__ perm, int E) {
  int e = blockIdx.x * 256 + threadIdx.x;
  if (e < E) {
    int p = atomicAdd(&cursor[etgt[e]], 1);
    perm[p] = e;
  }
}

// MFMA node table builder: C[M x 256] bf16 = X1@W1T^T [+ X2@W2T^T] [+ bias].
__global__ __launch_bounds__(256, 4) void node_mfma(
    const float* __restrict__ X1, const unsigned short* __restrict__ W1T,
    const float* __restrict__ X2, const unsigned short* __restrict__ W2T,
    const float* __restrict__ bias, unsigned short* __restrict__ C, int M)
{
  int tid = threadIdx.x;
  int w = tid >> 6, lane = tid & 63;
  int l15 = lane & 15, lg = lane >> 4;
  int grow = blockIdx.x * 64 + w * 16 + l15;   // this lane's input row
  int rowc = grow < M ? grow : 0;

  f32x4 acc[16];
#pragma unroll
  for (int f = 0; f < 16; f++) acc[f] = (f32x4){0.f, 0.f, 0.f, 0.f};

  for (int pass = 0; pass < 2; ++pass) {
    const float* X = pass ? X2 : X1;
    const unsigned short* WT = pass ? W2T : W1T;
    if (X == nullptr) break;
    const float* Xrow = X + (size_t)rowc * 128;
#pragma unroll
    for (int ks = 0; ks < 4; ks++) {
      int c0 = ks * 32 + lg * 8;
      float4 x0 = *(const float4*)&Xrow[c0];
      float4 x1 = *(const float4*)&Xrow[c0 + 4];
      bf16x8 a;
      a[0] = (short)f2bf(x0.x); a[1] = (short)f2bf(x0.y);
      a[2] = (short)f2bf(x0.z); a[3] = (short)f2bf(x0.w);
      a[4] = (short)f2bf(x1.x); a[5] = (short)f2bf(x1.y);
      a[6] = (short)f2bf(x1.z); a[7] = (short)f2bf(x1.w);
#pragma unroll
      for (int f = 0; f < 16; f++) {
        bf16x8 b = *(const bf16x8*)&WT[(size_t)(f * 16 + l15) * 128 + c0];
        acc[f] = __builtin_amdgcn_mfma_f32_16x16x32_bf16(a, b, acc[f], 0, 0, 0);
      }
    }
  }

  int rbase = blockIdx.x * 64 + w * 16 + lg * 4;
#pragma unroll
  for (int f = 0; f < 16; f++) {
    int col = f * 16 + l15;
    float bv = bias ? bias[col] : 0.f;
#pragma unroll
    for (int r = 0; r < 4; r++) {
      int row = rbase + r;
      if (row < M) C[(size_t)row * 256 + col] = f2bf(acc[f][r] + bv);
    }
  }
}

// Per-edge MFMA kernel over target-sorted edges: 64 edges per 256-thread block.
#define MSG_LD 136   // 128 + 8 bf16 pad (row = 272 B = 68 floats)
__global__ __launch_bounds__(256, 6) void edge_mfma(
    const unsigned short* __restrict__ A, const unsigned short* __restrict__ B,
    const float* __restrict__ w1c,
    const unsigned short* __restrict__ Wm2T, const float* __restrict__ bm2,
    const unsigned short* __restrict__ Wc1T, const float* __restrict__ bc1,
    const float* __restrict__ Wc2, const float* __restrict__ bc2,
    const float* __restrict__ pos_src, const float* __restrict__ pos_tgt,
    const int* __restrict__ esrc, const int* __restrict__ etgt,
    const int* __restrict__ perm,
    float* __restrict__ agg, float* __restrict__ vel, int E)
{
  __shared__ int ss[64], ts[64], segs[64], segtgt[66], segstart[66];
  __shared__ int nsegS;
  __shared__ float rels[64][4];
  __shared__ float velP[64][3];
  __shared__ float w1cS[256];
  __shared__ unsigned short msgs[64 * MSG_LD];  // phase3 aliases rows as c1 f32 (ld 68)

  int tid = threadIdx.x;
  int e0 = blockIdx.x * 64;

  w1cS[tid] = w1c[tid];
  if (tid < 64) {  // exactly wave 0
    int e = e0 + tid;
    int s = 0, t = -1;
    if (e < E) { int eid = perm[e]; s = esrc[eid]; t = etgt[eid]; }
    ss[tid] = s; ts[tid] = t;
    int tc = t < 0 ? 0 : t;
    float rx = pos_tgt[(size_t)tc * 3 + 0] - pos_src[(size_t)s * 3 + 0];
    float ry = pos_tgt[(size_t)tc * 3 + 1] - pos_src[(size_t)s * 3 + 1];
    float rz = pos_tgt[(size_t)tc * 3 + 2] - pos_src[(size_t)s * 3 + 2];
    rels[tid][0] = rx; rels[tid][1] = ry; rels[tid][2] = rz;
    rels[tid][3] = rx * rx + ry * ry + rz * rz;
    velP[tid][0] = 0.f; velP[tid][1] = 0.f; velP[tid][2] = 0.f;
    int tprev = __shfl_up(t, 1);
    int flag = (tid > 0 && t != tprev) ? 1 : 0;
    unsigned long long mask = __ballot(flag);
    int segid = (int)__popcll(mask & ((1ULL << tid) - 1ULL)) + flag;
    segs[tid] = segid;
    if (flag || tid == 0) { segtgt[segid] = t; segstart[segid] = tid; }
    if (tid == 0) {
      int n = (int)__popcll(mask) + 1;
      nsegS = n;
      segtgt[n] = -1;
      segstart[n] = 64;
    }
  }
  __syncthreads();

  int w = tid >> 6, lane = tid & 63;
  int l15 = lane & 15, lg = lane >> 4;
  int R0 = w * 16;

  // ---- fused phase 1+2 ----
  int hrow = R0 + l15;
  int s_n = ss[hrow];
  int t_n = ts[hrow] < 0 ? 0 : ts[hrow];
  float sq = rels[hrow][3];
  const unsigned short* Arow = &A[(size_t)s_n * 256];
  const unsigned short* Brow = &B[(size_t)t_n * 256];

  bf16x8 av[8], bv[8];
#pragma unroll
  for (int ks = 0; ks < 8; ks++) {
    int c0 = ks * 32 + lg * 8;
    av[ks] = *(const bf16x8*)&Arow[c0];
    bv[ks] = *(const bf16x8*)&Brow[c0];
  }

  f32x4 acc[8];
#pragma unroll
  for (int f = 0; f < 8; f++) acc[f] = (f32x4){0.f, 0.f, 0.f, 0.f};

#pragma unroll
  for (int ks = 0; ks < 8; ks++) {
    int c0 = ks * 32 + lg * 8;
    bf16x8 a;
#pragma unroll
    for (int j = 0; j < 8; j++) {
      float h = silu_f(bfs2f((unsigned short)av[ks][j]) + bfs2f((unsigned short)bv[ks][j])
                       + sq * w1cS[c0 + j]);
      a[j] = (short)f2bf(h);
    }
#pragma unroll
    for (int f = 0; f < 8; f++) {
      bf16x8 b = *(const bf16x8*)&Wm2T[(f * 16 + l15) * 256 + c0];
      acc[f] = __builtin_amdgcn_mfma_f32_16x16x32_bf16(a, b, acc[f], 0, 0, 0);
    }
  }

  // epilogue: silu+bias -> msgs (bf16, LDS). No global atomics here.
#pragma unroll
  for (int f = 0; f < 8; f++) {
    int col = f * 16 + l15;
    float bias = bm2[col];
#pragma unroll
    for (int r = 0; r < 4; r++) {
      int row = R0 + lg * 4 + r;
      float v = silu_f(acc[f][r] + bias);
      msgs[row * MSG_LD + col] = f2bf(v);
    }
  }
  __syncthreads();

  // agg: per-block LDS segment-sum -> one global atomic per (seg, col).
  int nseg = nsegS;
  {
    int col = tid & 127;
    for (int s = tid >> 7; s < nseg; s += 2) {
      int t = segtgt[s];
      if (t < 0) continue;
      int r0 = segstart[s], r1 = segstart[s + 1];
      float sum = 0.f;
      for (int r = r0; r < r1; r++) sum += bfs2f(msgs[r * MSG_LD + col]);
      atomicAdd(&agg[(size_t)t * 128 + col], sum);
    }
  }
  __syncthreads();

  // phase 3: c1(64x64) = silu(msg(64x128) @ Wc1(128x64) + bc1), MFMA
  f32x4 acc2[4];
#pragma unroll
  for (int f = 0; f < 4; f++) acc2[f] = (f32x4){0.f, 0.f, 0.f, 0.f};
  {
    const unsigned short* mrow = &msgs[hrow * MSG_LD];
#pragma unroll
    for (int ks = 0; ks < 4; ks++) {
      int kb = ks * 32 + lg * 8;
      bf16x8 a = *(const bf16x8*)&mrow[kb];
#pragma unroll
      for (int f = 0; f < 4; f++) {
        bf16x8 b = *(const bf16x8*)&Wc1T[(f * 16 + l15) * 128 + kb];
        acc2[f] = __builtin_amdgcn_mfma_f32_16x16x32_bf16(a, b, acc2[f], 0, 0, 0);
      }
    }
  }
  float* c1 = (float*)msgs;
#pragma unroll
  for (int f = 0; f < 4; f++) {
    int col = f * 16 + l15;
    float bias = bc1[col];
#pragma unroll
    for (int r = 0; r < 4; r++) {
      int row = R0 + lg * 4 + r;
      c1[row * 68 + col] = silu_f(acc2[f][r] + bias);
    }
  }
  __syncthreads();

  // phase 4: wgt = tanh(c1 @ Wc2 + bc2); velP[seg] += wgt * rel
  {
    int row = tid >> 2, sub = tid & 3;
    const float* crow = &c1[row * 68 + sub * 16];
    float dot = 0.f;
#pragma unroll
    for (int k = 0; k < 16; k++) dot = fmaf(crow[k], Wc2[sub * 16 + k], dot);
    dot += __shfl_xor(dot, 1);
    dot += __shfl_xor(dot, 2);
    if (sub == 0 && e0 + row < E) {
      float wv = tanhf(dot + bc2[0]);
      int sg = segs[row];
      atomicAdd(&velP[sg][0], wv * rels[row][0]);
      atomicAdd(&velP[sg][1], wv * rels[row][1]);
      atomicAdd(&velP[sg][2], wv * rels[row][2]);
    }
  }
  __syncthreads();
  if (tid < 3 * nseg) {
    int s = tid / 3, k = tid - 3 * s;
    int t = segtgt[s];
    if (t >= 0) atomicAdd(&vel[(size_t)t * 3 + k], velP[s][k]);
  }
}

// MFMA per-target update MLP + layernorm. 64 targets/block, 4 waves x 16 rows.
// Wu1T[n=128][k=256] (k<128: h_tgt, k>=128: agg), Wu2T[n=128][k=128].
__global__ __launch_bounds__(256, 4) void tgt_mfma(
    const float* __restrict__ h_tgt, const float* __restrict__ agg,
    const unsigned short* __restrict__ Wu1T, const float* __restrict__ bu1,
    const unsigned short* __restrict__ Wu2T, const float* __restrict__ bu2,
    const float* __restrict__ gamma, const float* __restrict__ beta,
    float* __restrict__ out, int M)
{
  __shared__ unsigned short u1s[64 * MSG_LD];  // 17408 B

  int tid = threadIdx.x;
  int w = tid >> 6, lane = tid & 63;
  int l15 = lane & 15, lg = lane >> 4;
  int R0 = w * 16;
  int grow = blockIdx.x * 64 + R0 + l15;
  int rowc = grow < M ? grow : M - 1;

  const float* Xrow = h_tgt + (size_t)rowc * 128;
  const float* Grow = agg + (size_t)rowc * 128;

  // GEMM1: u1(64x128) = silu([h|agg](64x256) @ Wu1 + bu1)
  f32x4 acc[8];
#pragma unroll
  for (int f = 0; f < 8; f++) acc[f] = (f32x4){0.f, 0.f, 0.f, 0.f};
#pragma unroll
  for (int ks = 0; ks < 8; ks++) {
    int c0 = ks * 32 + lg * 8;             // k 0..255
    const float* src = (c0 < 128) ? &Xrow[c0] : &Grow[c0 - 128];
    float4 x0 = *(const float4*)&src[0];
    float4 x1 = *(const float4*)&src[4];
    bf16x8 a;
    a[0] = (short)f2bf(x0.x); a[1] = (short)f2bf(x0.y);
    a[2] = (short)f2bf(x0.z); a[3] = (short)f2bf(x0.w);
    a[4] = (short)f2bf(x1.x); a[5] = (short)f2bf(x1.y);
    a[6] = (short)f2bf(x1.z); a[7] = (short)f2bf(x1.w);
#pragma unroll
    for (int f = 0; f < 8; f++) {
      bf16x8 b = *(const bf16x8*)&Wu1T[(size_t)(f * 16 + l15) * 256 + c0];
      acc[f] = __builtin_amdgcn_mfma_f32_16x16x32_bf16(a, b, acc[f], 0, 0, 0);
    }
  }
#pragma unroll
  for (int f = 0; f < 8; f++) {
    int col = f * 16 + l15;
    float bias = bu1[col];
#pragma unroll
    for (int r = 0; r < 4; r++) {
      int row = R0 + lg * 4 + r;
      u1s[row * MSG_LD + col] = f2bf(silu_f(acc[f][r] + bias));
    }
  }
  __syncthreads();

  // GEMM2: upd(64x128) = u1(64x128) @ Wu2 + bu2
  f32x4 acc2[8];
#pragma unroll
  for (int f = 0; f < 8; f++) acc2[f] = (f32x4){0.f, 0.f, 0.f, 0.f};
  {
    const unsigned short* urow = &u1s[(R0 + l15) * MSG_LD];
#pragma unroll
    for (int ks = 0; ks < 4; ks++) {
      int kb = ks * 32 + lg * 8;
      bf16x8 a = *(const bf16x8*)&urow[kb];
#pragma unroll
      for (int f = 0; f < 8; f++) {
        bf16x8 b = *(const bf16x8*)&Wu2T[(size_t)(f * 16 + l15) * 128 + kb];
        acc2[f] = __builtin_amdgcn_mfma_f32_16x16x32_bf16(a, b, acc2[f], 0, 0, 0);
      }
    }
  }

  // epilogue: x = h_tgt + upd; layernorm per row (16-lane shfl reduce)
#pragma unroll
  for (int r = 0; r < 4; r++) {
    int row = blockIdx.x * 64 + R0 + lg * 4 + r;
    bool ok = row < M;
    int rc = ok ? row : M - 1;
    float x[8];
    float s = 0.f, s2 = 0.f;
#pragma unroll
    for (int f = 0; f < 8; f++) {
      int col = f * 16 + l15;
      float v = acc2[f][r] + bu2[col] + h_tgt[(size_t)rc * 128 + col];
      x[f] = v; s += v; s2 += v * v;
    }
    s += __shfl_xor(s, 1);  s2 += __shfl_xor(s2, 1);
    s += __shfl_xor(s, 2);  s2 += __shfl_xor(s2, 2);
    s += __shfl_xor(s, 4);  s2 += __shfl_xor(s2, 4);
    s += __shfl_xor(s, 8);  s2 += __shfl_xor(s2, 8);
    float mu = s * (1.f / 128.f);
    float var = s2 * (1.f / 128.f) - mu * mu;
    float rs = rsqrtf(var + 1e-5f);
    if (ok) {
#pragma unroll
      for (int f = 0; f < 8; f++) {
        int col = f * 16 + l15;
        out[(size_t)row * 128 + col] = (x[f] - mu) * rs * gamma[col] + beta[col];
      }
    }
  }
}

extern "C" void kernel_launch(void* const* d_in, const int* in_sizes, int n_in,
                              void* d_out, int out_size, void* d_ws, size_t ws_size,
                              hipStream_t stream) {
  const float* h_src  = (const float*)d_in[0];
  const float* h_tgt  = (const float*)d_in[1];
  const float* pos_src = (const float*)d_in[2];
  const float* pos_tgt = (const float*)d_in[3];
  const float* t_emb  = (const float*)d_in[4];
  const float* W_m1 = (const float*)d_in[5];
  const float* b_m1 = (const float*)d_in[6];
  const float* W_m2 = (const float*)d_in[7];
  const float* b_m2 = (const float*)d_in[8];
  const float* W_c1 = (const float*)d_in[9];
  const float* b_c1 = (const float*)d_in[10];
  const float* W_c2 = (const float*)d_in[11];
  const float* b_c2 = (const float*)d_in[12];
  const float* W_u1 = (const float*)d_in[13];
  const float* b_u1 = (const float*)d_in[14];
  const float* W_u2 = (const float*)d_in[15];
  const float* b_u2 = (const float*)d_in[16];
  const float* gamma = (const float*)d_in[17];
  const float* beta  = (const float*)d_in[18];
  const int* esrc = (const int*)d_in[19];
  const int* etgt = (const int*)d_in[20];

  int n_src = in_sizes[0] / 128;
  int n_tgt = in_sizes[1] / 128;
  int E = in_sizes[19];

  // workspace layout
  unsigned short* A    = (unsigned short*)d_ws;                 // n_src*256 bf16
  unsigned short* B    = A + (size_t)n_src * 256;               // n_tgt*256 bf16
  unsigned short* Wm2T = B + (size_t)n_tgt * 256;               // 128*256 bf16
  unsigned short* Wc1T = Wm2T + 128 * 256;                      // 64*128 bf16
  unsigned short* W1aT = Wc1T + 64 * 128;                       // 256*128 bf16
  unsigned short* W1bT = W1aT + 256 * 128;                      // 256*128 bf16
  unsigned short* W1dT = W1bT + 256 * 128;                      // 256*128 bf16
  unsigned short* Wu1T = W1dT + 256 * 128;                      // 128*256 bf16
  unsigned short* Wu2T = Wu1T + 128 * 256;                      // 128*128 bf16
  float* agg  = (float*)(Wu2T + 128 * 128);                     // n_tgt*128 f32
  int* cnt    = (int*)(agg + (size_t)n_tgt * 128);              // n_tgt
  int* cursor = cnt + n_tgt;                                    // n_tgt
  int* perm   = cursor + n_tgt;                                 // E
  float* out_h = (float*)d_out;                                 // n_tgt x 128
  float* vel = out_h + (size_t)n_tgt * 128;                     // n_tgt x 3

  hipMemsetAsync(agg, 0, (size_t)n_tgt * 128 * sizeof(float), stream);
  hipMemsetAsync(vel, 0, (size_t)n_tgt * 3 * sizeof(float), stream);
  hipMemsetAsync(cnt, 0, (size_t)n_tgt * sizeof(int), stream);

  dim3 blk(256);
  prep_weights<<<128, blk, 0, stream>>>(W_m2, W_c1, W_m1, W_u1, W_u2,
                                        Wm2T, Wc1T, W1aT, W1bT, W1dT, Wu1T, Wu2T);
  count_edges<<<(E + 255) / 256, blk, 0, stream>>>(etgt, cnt, E);
  scan_bins<<<1, blk, 0, stream>>>(cnt, cursor, n_tgt);
  scatter_edges<<<(E + 255) / 256, blk, 0, stream>>>(etgt, cursor, perm, E);
  node_mfma<<<(n_src + 63) / 64, blk, 0, stream>>>(
      h_src, W1aT, nullptr, nullptr, nullptr, A, n_src);
  node_mfma<<<(n_tgt + 63) / 64, blk, 0, stream>>>(
      h_tgt, W1bT, t_emb, W1dT, b_m1, B, n_tgt);
  edge_mfma<<<(E + 63) / 64, blk, 0, stream>>>(
      A, B, W_m1 + 256 * 256, Wm2T, b_m2, Wc1T, b_c1, W_c2, b_c2,
      pos_src, pos_tgt, esrc, etgt, perm, agg, vel, E);
  tgt_mfma<<<(n_tgt + 63) / 64, blk, 0, stream>>>(
      h_tgt, agg, Wu1T, b_u1, Wu2T, b_u2, gamma, beta, out_h, n_tgt);
}

// Round 14
// 867.130 us; speedup vs baseline: 1.6556x; 1.1859x over previous
//
#include <hip/hip_runtime.h>

typedef __attribute__((ext_vector_type(8))) short bf16x8;
typedef __attribute__((ext_vector_type(4))) float f32x4;

__device__ __forceinline__ float silu_f(float x) {
  return x / (1.0f + __expf(-x));
}

__device__ __forceinline__ unsigned short f2bf(float f) {
  union { float f; unsigned int u; } x; x.f = f;
  unsigned int u = x.u + 0x7fffu + ((x.u >> 16) & 1u);  // RNE
  return (unsigned short)(u >> 16);
}

__device__ __forceinline__ float bfs2f(unsigned short s) {
  return __uint_as_float((unsigned int)s << 16);
}

// Transpose+convert all weights to bf16 [n][k] layouts for MFMA B-operands.
__global__ void prep_weights(const float* __restrict__ Wm2, const float* __restrict__ Wc1,
                             const float* __restrict__ Wm1,
                             const float* __restrict__ Wu1, const float* __restrict__ Wu2,
                             unsigned short* __restrict__ Wm2T, unsigned short* __restrict__ Wc1T,
                             unsigned short* __restrict__ W1aT, unsigned short* __restrict__ W1bT,
                             unsigned short* __restrict__ W1dT,
                             unsigned short* __restrict__ Wu1T, unsigned short* __restrict__ Wu2T)
{
  int i = blockIdx.x * 256 + threadIdx.x;   // grid covers 32768
  if (i < 128 * 256) {
    int n = i >> 8, k = i & 255;
    Wm2T[i] = f2bf(Wm2[k * 128 + n]);
    Wu1T[i] = f2bf(Wu1[(size_t)k * 128 + n]);   // Wu1 is 256x128
  }
  if (i < 64 * 128) {
    int n = i >> 7, k = i & 127;
    Wc1T[i] = f2bf(Wc1[k * 64 + n]);
  }
  if (i < 128 * 128) {
    int n = i >> 7, k = i & 127;
    Wu2T[i] = f2bf(Wu2[k * 128 + n]);
  }
  if (i < 256 * 128) {
    int n = i >> 7, k = i & 127;
    W1aT[i] = f2bf(Wm1[(size_t)k * 256 + n]);
    W1bT[i] = f2bf(Wm1[(size_t)(128 + k) * 256 + n]);
    W1dT[i] = f2bf(Wm1[(size_t)(257 + k) * 256 + n]);
  }
}

// ---- counting sort of edges by target ----
__global__ void count_edges(const int* __restrict__ etgt, int* __restrict__ cnt, int E) {
  int e = blockIdx.x * 256 + threadIdx.x;
  if (e < E) atomicAdd(&cnt[etgt[e]], 1);
}

__global__ void scan_bins(const int* __restrict__ cnt, int* __restrict__ cursor, int n) {
  __shared__ int sums[256];
  int tid = threadIdx.x;
  int chunk = (n + 255) >> 8;
  int lo = tid * chunk, hi = min(lo + chunk, n);
  int s = 0;
  for (int i = lo; i < hi; i++) s += cnt[i];
  sums[tid] = s;
  __syncthreads();
  if (tid == 0) {
    int acc = 0;
    for (int i = 0; i < 256; i++) { int t = sums[i]; sums[i] = acc; acc += t; }
  }
  __syncthreads();
  int run = sums[tid];
  for (int i = lo; i < hi; i++) { int c = cnt[i]; cursor[i] = run; run += c; }
}

__global__ void scatter_edges(const int* __restrict__ etgt, int* __restrict__ cursor,
                              int* __restrict__ perm, int E) {
  int e = blockIdx.x * 256 + threadIdx.x;
  if (e < E) {
    int p = atomicAdd(&cursor[etgt[e]], 1);
    perm[p] = e;
  }
}

// MFMA node table builder: C[M x 256] bf16 = X1@W1T^T [+ X2@W2T^T] [+ bias].
__global__ __launch_bounds__(256, 4) void node_mfma(
    const float* __restrict__ X1, const unsigned short* __restrict__ W1T,
    const float* __restrict__ X2, const unsigned short* __restrict__ W2T,
    const float* __restrict__ bias, unsigned short* __restrict__ C, int M)
{
  int tid = threadIdx.x;
  int w = tid >> 6, lane = tid & 63;
  int l15 = lane & 15, lg = lane >> 4;
  int grow = blockIdx.x * 64 + w * 16 + l15;   // this lane's input row
  int rowc = grow < M ? grow : 0;

  f32x4 acc[16];
#pragma unroll
  for (int f = 0; f < 16; f++) acc[f] = (f32x4){0.f, 0.f, 0.f, 0.f};

  for (int pass = 0; pass < 2; ++pass) {
    const float* X = pass ? X2 : X1;
    const unsigned short* WT = pass ? W2T : W1T;
    if (X == nullptr) break;
    const float* Xrow = X + (size_t)rowc * 128;
#pragma unroll
    for (int ks = 0; ks < 4; ks++) {
      int c0 = ks * 32 + lg * 8;
      float4 x0 = *(const float4*)&Xrow[c0];
      float4 x1 = *(const float4*)&Xrow[c0 + 4];
      bf16x8 a;
      a[0] = (short)f2bf(x0.x); a[1] = (short)f2bf(x0.y);
      a[2] = (short)f2bf(x0.z); a[3] = (short)f2bf(x0.w);
      a[4] = (short)f2bf(x1.x); a[5] = (short)f2bf(x1.y);
      a[6] = (short)f2bf(x1.z); a[7] = (short)f2bf(x1.w);
#pragma unroll
      for (int f = 0; f < 16; f++) {
        bf16x8 b = *(const bf16x8*)&WT[(size_t)(f * 16 + l15) * 128 + c0];
        acc[f] = __builtin_amdgcn_mfma_f32_16x16x32_bf16(a, b, acc[f], 0, 0, 0);
      }
    }
  }

  int rbase = blockIdx.x * 64 + w * 16 + lg * 4;
#pragma unroll
  for (int f = 0; f < 16; f++) {
    int col = f * 16 + l15;
    float bv = bias ? bias[col] : 0.f;
#pragma unroll
    for (int r = 0; r < 4; r++) {
      int row = rbase + r;
      if (row < M) C[(size_t)row * 256 + col] = f2bf(acc[f][r] + bv);
    }
  }
}

// Per-edge MFMA kernel over target-sorted edges.
// 128 edges/block, 4 waves; each wave owns 32 rows (2 row-groups) so every
// Wm2T/Wc1T B-fragment load feeds TWO MFMAs (halves weight re-streaming).
#define EPB 128
#define MSG_LD 136   // 128 + 8 bf16 pad (row = 272 B = 68 floats)
__global__ __launch_bounds__(256, 3) void edge_mfma(
    const unsigned short* __restrict__ A, const unsigned short* __restrict__ B,
    const float* __restrict__ w1c,
    const unsigned short* __restrict__ Wm2T, const float* __restrict__ bm2,
    const unsigned short* __restrict__ Wc1T, const float* __restrict__ bc1,
    const float* __restrict__ Wc2, const float* __restrict__ bc2,
    const float* __restrict__ pos_src, const float* __restrict__ pos_tgt,
    const int* __restrict__ esrc, const int* __restrict__ etgt,
    const int* __restrict__ perm,
    float* __restrict__ agg, float* __restrict__ vel, int E)
{
  __shared__ int ss[EPB], ts[EPB], segs[EPB], segtgt[EPB + 2], segstart[EPB + 2];
  __shared__ int nsegS;
  __shared__ float rels[EPB][4];
  __shared__ float velP[EPB][3];
  __shared__ float w1cS[256];
  __shared__ unsigned short msgs[EPB * MSG_LD];  // 34816 B; phase3 aliases as c1 f32 (ld 68)

  int tid = threadIdx.x;
  int e0 = blockIdx.x * EPB;

  w1cS[tid] = w1c[tid];
  if (tid < EPB) {
    int e = e0 + tid;
    int s = 0, t = -1;
    if (e < E) { int eid = perm[e]; s = esrc[eid]; t = etgt[eid]; }
    ss[tid] = s; ts[tid] = t;
    int tc = t < 0 ? 0 : t;
    float rx = pos_tgt[(size_t)tc * 3 + 0] - pos_src[(size_t)s * 3 + 0];
    float ry = pos_tgt[(size_t)tc * 3 + 1] - pos_src[(size_t)s * 3 + 1];
    float rz = pos_tgt[(size_t)tc * 3 + 2] - pos_src[(size_t)s * 3 + 2];
    rels[tid][0] = rx; rels[tid][1] = ry; rels[tid][2] = rz;
    rels[tid][3] = rx * rx + ry * ry + rz * rz;
    velP[tid][0] = 0.f; velP[tid][1] = 0.f; velP[tid][2] = 0.f;
  }
  __syncthreads();

  // segmentation over 128 sorted entries: wave 0, two ballot passes over LDS ts[]
  if (tid < 64) {
    int t0 = ts[tid];
    int flag0 = (tid > 0 && t0 != ts[tid - 1]) ? 1 : 0;
    unsigned long long m0 = __ballot(flag0);
    int seg0 = (int)__popcll(m0 & ((1ULL << tid) - 1ULL)) + flag0;
    segs[tid] = seg0;
    if (flag0 || tid == 0) { segtgt[seg0] = t0; segstart[seg0] = tid; }
    int n0 = (int)__popcll(m0) + 1;
    int t1 = ts[64 + tid];
    int flag1 = (t1 != ts[63 + tid]) ? 1 : 0;
    unsigned long long m1 = __ballot(flag1);
    int seg1 = n0 - 1 + (int)__popcll(m1 & ((1ULL << tid) - 1ULL)) + flag1;
    segs[64 + tid] = seg1;
    if (flag1) { segtgt[seg1] = t1; segstart[seg1] = 64 + tid; }
    if (tid == 0) {
      int n = n0 + (int)__popcll(m1);
      nsegS = n;
      segtgt[n] = -1;
      segstart[n] = EPB;
    }
  }
  __syncthreads();

  int w = tid >> 6, lane = tid & 63;
  int l15 = lane & 15, lg = lane >> 4;
  int RW = w * 32;   // wave's 32 rows

  // ---- fused phase 1+2, two row-groups share each B-fragment ----
  int hr0 = RW + l15, hr1 = RW + 16 + l15;
  const unsigned short* A0 = &A[(size_t)ss[hr0] * 256];
  const unsigned short* B0 = &B[(size_t)(ts[hr0] < 0 ? 0 : ts[hr0]) * 256];
  const unsigned short* A1 = &A[(size_t)ss[hr1] * 256];
  const unsigned short* B1 = &B[(size_t)(ts[hr1] < 0 ? 0 : ts[hr1]) * 256];
  float sq0 = rels[hr0][3], sq1 = rels[hr1][3];

  f32x4 acc0[8], acc1[8];
#pragma unroll
  for (int f = 0; f < 8; f++) {
    acc0[f] = (f32x4){0.f, 0.f, 0.f, 0.f};
    acc1[f] = (f32x4){0.f, 0.f, 0.f, 0.f};
  }

#pragma unroll
  for (int ks = 0; ks < 8; ks++) {
    int c0 = ks * 32 + lg * 8;
    bf16x8 a0v = *(const bf16x8*)&A0[c0];
    bf16x8 b0v = *(const bf16x8*)&B0[c0];
    bf16x8 a1v = *(const bf16x8*)&A1[c0];
    bf16x8 b1v = *(const bf16x8*)&B1[c0];
    bf16x8 h0, h1;
#pragma unroll
    for (int j = 0; j < 8; j++) {
      float wv = w1cS[c0 + j];
      h0[j] = (short)f2bf(silu_f(bfs2f((unsigned short)a0v[j]) + bfs2f((unsigned short)b0v[j]) + sq0 * wv));
      h1[j] = (short)f2bf(silu_f(bfs2f((unsigned short)a1v[j]) + bfs2f((unsigned short)b1v[j]) + sq1 * wv));
    }
#pragma unroll
    for (int f = 0; f < 8; f++) {
      bf16x8 b = *(const bf16x8*)&Wm2T[(f * 16 + l15) * 256 + c0];
      acc0[f] = __builtin_amdgcn_mfma_f32_16x16x32_bf16(h0, b, acc0[f], 0, 0, 0);
      acc1[f] = __builtin_amdgcn_mfma_f32_16x16x32_bf16(h1, b, acc1[f], 0, 0, 0);
    }
  }

  // epilogue: silu+bias -> msgs (bf16, LDS)
#pragma unroll
  for (int f = 0; f < 8; f++) {
    int col = f * 16 + l15;
    float bias = bm2[col];
#pragma unroll
    for (int r = 0; r < 4; r++) {
      int row0 = RW + lg * 4 + r;
      int row1 = RW + 16 + lg * 4 + r;
      msgs[row0 * MSG_LD + col] = f2bf(silu_f(acc0[f][r] + bias));
      msgs[row1 * MSG_LD + col] = f2bf(silu_f(acc1[f][r] + bias));
    }
  }
  __syncthreads();

  // agg: per-block LDS segment-sum -> one global atomic per (seg, col).
  int nseg = nsegS;
  {
    int col = tid & 127;
    for (int s = tid >> 7; s < nseg; s += 2) {
      int t = segtgt[s];
      if (t < 0) continue;
      int r0 = segstart[s], r1 = segstart[s + 1];
      float sum = 0.f;
      for (int r = r0; r < r1; r++) sum += bfs2f(msgs[r * MSG_LD + col]);
      atomicAdd(&agg[(size_t)t * 128 + col], sum);
    }
  }
  __syncthreads();  // segment-sum reads done before c1 aliases msgs

  // phase 3: c1(128x64) = silu(msg(128x128) @ Wc1(128x64) + bc1); B-frag shared by 2 rg
  f32x4 acc20[4], acc21[4];
#pragma unroll
  for (int f = 0; f < 4; f++) {
    acc20[f] = (f32x4){0.f, 0.f, 0.f, 0.f};
    acc21[f] = (f32x4){0.f, 0.f, 0.f, 0.f};
  }
  {
    const unsigned short* m0 = &msgs[hr0 * MSG_LD];
    const unsigned short* m1 = &msgs[hr1 * MSG_LD];
#pragma unroll
    for (int ks = 0; ks < 4; ks++) {
      int kb = ks * 32 + lg * 8;
      bf16x8 a0 = *(const bf16x8*)&m0[kb];
      bf16x8 a1 = *(const bf16x8*)&m1[kb];
#pragma unroll
      for (int f = 0; f < 4; f++) {
        bf16x8 b = *(const bf16x8*)&Wc1T[(f * 16 + l15) * 128 + kb];
        acc20[f] = __builtin_amdgcn_mfma_f32_16x16x32_bf16(a0, b, acc20[f], 0, 0, 0);
        acc21[f] = __builtin_amdgcn_mfma_f32_16x16x32_bf16(a1, b, acc21[f], 0, 0, 0);
      }
    }
  }
  // c1 aliases msgs row-for-row (272 B = 68 floats); waves touch disjoint rows,
  // and this wave's msgs reads (above) precede its c1 writes in program order.
  float* c1 = (float*)msgs;
#pragma unroll
  for (int f = 0; f < 4; f++) {
    int col = f * 16 + l15;
    float bias = bc1[col];
#pragma unroll
    for (int r = 0; r < 4; r++) {
      int row0 = RW + lg * 4 + r;
      int row1 = RW + 16 + lg * 4 + r;
      c1[row0 * 68 + col] = silu_f(acc20[f][r] + bias);
      c1[row1 * 68 + col] = silu_f(acc21[f][r] + bias);
    }
  }
  __syncthreads();

  // phase 4: wgt = tanh(c1 @ Wc2 + bc2); velP[seg] += wgt * rel. 2 threads/row.
  {
    int row = tid >> 1, sub = tid & 1;
    const float* crow = &c1[row * 68 + sub * 32];
    float dot = 0.f;
#pragma unroll
    for (int k = 0; k < 32; k++) dot = fmaf(crow[k], Wc2[sub * 32 + k], dot);
    dot += __shfl_xor(dot, 1);
    if (sub == 0 && e0 + row < E) {
      float wv = tanhf(dot + bc2[0]);
      int sg = segs[row];
      atomicAdd(&velP[sg][0], wv * rels[row][0]);
      atomicAdd(&velP[sg][1], wv * rels[row][1]);
      atomicAdd(&velP[sg][2], wv * rels[row][2]);
    }
  }
  __syncthreads();
  for (int i = tid; i < 3 * nseg; i += 256) {
    int s = i / 3, k = i - 3 * s;
    int t = segtgt[s];
    if (t >= 0) atomicAdd(&vel[(size_t)t * 3 + k], velP[s][k]);
  }
}

// MFMA per-target update MLP + layernorm. 64 targets/block, 4 waves x 16 rows.
__global__ __launch_bounds__(256, 4) void tgt_mfma(
    const float* __restrict__ h_tgt, const float* __restrict__ agg,
    const unsigned short* __restrict__ Wu1T, const float* __restrict__ bu1,
    const unsigned short* __restrict__ Wu2T, const float* __restrict__ bu2,
    const float* __restrict__ gamma, const float* __restrict__ beta,
    float* __restrict__ out, int M)
{
  __shared__ unsigned short u1s[64 * MSG_LD];  // 17408 B

  int tid = threadIdx.x;
  int w = tid >> 6, lane = tid & 63;
  int l15 = lane & 15, lg = lane >> 4;
  int R0 = w * 16;
  int grow = blockIdx.x * 64 + R0 + l15;
  int rowc = grow < M ? grow : M - 1;

  const float* Xrow = h_tgt + (size_t)rowc * 128;
  const float* Grow = agg + (size_t)rowc * 128;

  // GEMM1: u1(64x128) = silu([h|agg](64x256) @ Wu1 + bu1)
  f32x4 acc[8];
#pragma unroll
  for (int f = 0; f < 8; f++) acc[f] = (f32x4){0.f, 0.f, 0.f, 0.f};
#pragma unroll
  for (int ks = 0; ks < 8; ks++) {
    int c0 = ks * 32 + lg * 8;             // k 0..255
    const float* src = (c0 < 128) ? &Xrow[c0] : &Grow[c0 - 128];
    float4 x0 = *(const float4*)&src[0];
    float4 x1 = *(const float4*)&src[4];
    bf16x8 a;
    a[0] = (short)f2bf(x0.x); a[1] = (short)f2bf(x0.y);
    a[2] = (short)f2bf(x0.z); a[3] = (short)f2bf(x0.w);
    a[4] = (short)f2bf(x1.x); a[5] = (short)f2bf(x1.y);
    a[6] = (short)f2bf(x1.z); a[7] = (short)f2bf(x1.w);
#pragma unroll
    for (int f = 0; f < 8; f++) {
      bf16x8 b = *(const bf16x8*)&Wu1T[(size_t)(f * 16 + l15) * 256 + c0];
      acc[f] = __builtin_amdgcn_mfma_f32_16x16x32_bf16(a, b, acc[f], 0, 0, 0);
    }
  }
#pragma unroll
  for (int f = 0; f < 8; f++) {
    int col = f * 16 + l15;
    float bias = bu1[col];
#pragma unroll
    for (int r = 0; r < 4; r++) {
      int row = R0 + lg * 4 + r;
      u1s[row * MSG_LD + col] = f2bf(silu_f(acc[f][r] + bias));
    }
  }
  __syncthreads();

  // GEMM2: upd(64x128) = u1(64x128) @ Wu2 + bu2
  f32x4 acc2[8];
#pragma unroll
  for (int f = 0; f < 8; f++) acc2[f] = (f32x4){0.f, 0.f, 0.f, 0.f};
  {
    const unsigned short* urow = &u1s[(R0 + l15) * MSG_LD];
#pragma unroll
    for (int ks = 0; ks < 4; ks++) {
      int kb = ks * 32 + lg * 8;
      bf16x8 a = *(const bf16x8*)&urow[kb];
#pragma unroll
      for (int f = 0; f < 8; f++) {
        bf16x8 b = *(const bf16x8*)&Wu2T[(size_t)(f * 16 + l15) * 128 + kb];
        acc2[f] = __builtin_amdgcn_mfma_f32_16x16x32_bf16(a, b, acc2[f], 0, 0, 0);
      }
    }
  }

  // epilogue: x = h_tgt + upd; layernorm per row (16-lane shfl reduce)
#pragma unroll
  for (int r = 0; r < 4; r++) {
    int row = blockIdx.x * 64 + R0 + lg * 4 + r;
    bool ok = row < M;
    int rc = ok ? row : M - 1;
    float x[8];
    float s = 0.f, s2 = 0.f;
#pragma unroll
    for (int f = 0; f < 8; f++) {
      int col = f * 16 + l15;
      float v = acc2[f][r] + bu2[col] + h_tgt[(size_t)rc * 128 + col];
      x[f] = v; s += v; s2 += v * v;
    }
    s += __shfl_xor(s, 1);  s2 += __shfl_xor(s2, 1);
    s += __shfl_xor(s, 2);  s2 += __shfl_xor(s2, 2);
    s += __shfl_xor(s, 4);  s2 += __shfl_xor(s2, 4);
    s += __shfl_xor(s, 8);  s2 += __shfl_xor(s2, 8);
    float mu = s * (1.f / 128.f);
    float var = s2 * (1.f / 128.f) - mu * mu;
    float rs = rsqrtf(var + 1e-5f);
    if (ok) {
#pragma unroll
      for (int f = 0; f < 8; f++) {
        int col = f * 16 + l15;
        out[(size_t)row * 128 + col] = (x[f] - mu) * rs * gamma[col] + beta[col];
      }
    }
  }
}

extern "C" void kernel_launch(void* const* d_in, const int* in_sizes, int n_in,
                              void* d_out, int out_size, void* d_ws, size_t ws_size,
                              hipStream_t stream) {
  const float* h_src  = (const float*)d_in[0];
  const float* h_tgt  = (const float*)d_in[1];
  const float* pos_src = (const float*)d_in[2];
  const float* pos_tgt = (const float*)d_in[3];
  const float* t_emb  = (const float*)d_in[4];
  const float* W_m1 = (const float*)d_in[5];
  const float* b_m1 = (const float*)d_in[6];
  const float* W_m2 = (const float*)d_in[7];
  const float* b_m2 = (const float*)d_in[8];
  const float* W_c1 = (const float*)d_in[9];
  const float* b_c1 = (const float*)d_in[10];
  const float* W_c2 = (const float*)d_in[11];
  const float* b_c2 = (const float*)d_in[12];
  const float* W_u1 = (const float*)d_in[13];
  const float* b_u1 = (const float*)d_in[14];
  const float* W_u2 = (const float*)d_in[15];
  const float* b_u2 = (const float*)d_in[16];
  const float* gamma = (const float*)d_in[17];
  const float* beta  = (const float*)d_in[18];
  const int* esrc = (const int*)d_in[19];
  const int* etgt = (const int*)d_in[20];

  int n_src = in_sizes[0] / 128;
  int n_tgt = in_sizes[1] / 128;
  int E = in_sizes[19];

  // workspace layout
  unsigned short* A    = (unsigned short*)d_ws;                 // n_src*256 bf16
  unsigned short* B    = A + (size_t)n_src * 256;               // n_tgt*256 bf16
  unsigned short* Wm2T = B + (size_t)n_tgt * 256;               // 128*256 bf16
  unsigned short* Wc1T = Wm2T + 128 * 256;                      // 64*128 bf16
  unsigned short* W1aT = Wc1T + 64 * 128;                       // 256*128 bf16
  unsigned short* W1bT = W1aT + 256 * 128;                      // 256*128 bf16
  unsigned short* W1dT = W1bT + 256 * 128;                      // 256*128 bf16
  unsigned short* Wu1T = W1dT + 256 * 128;                      // 128*256 bf16
  unsigned short* Wu2T = Wu1T + 128 * 256;                      // 128*128 bf16
  float* agg  = (float*)(Wu2T + 128 * 128);                     // n_tgt*128 f32
  int* cnt    = (int*)(agg + (size_t)n_tgt * 128);              // n_tgt
  int* cursor = cnt + n_tgt;                                    // n_tgt
  int* perm   = cursor + n_tgt;                                 // E
  float* out_h = (float*)d_out;                                 // n_tgt x 128
  float* vel = out_h + (size_t)n_tgt * 128;                     // n_tgt x 3

  hipMemsetAsync(agg, 0, (size_t)n_tgt * 128 * sizeof(float), stream);
  hipMemsetAsync(vel, 0, (size_t)n_tgt * 3 * sizeof(float), stream);
  hipMemsetAsync(cnt, 0, (size_t)n_tgt * sizeof(int), stream);

  dim3 blk(256);
  prep_weights<<<128, blk, 0, stream>>>(W_m2, W_c1, W_m1, W_u1, W_u2,
                                        Wm2T, Wc1T, W1aT, W1bT, W1dT, Wu1T, Wu2T);
  count_edges<<<(E + 255) / 256, blk, 0, stream>>>(etgt, cnt, E);
  scan_bins<<<1, blk, 0, stream>>>(cnt, cursor, n_tgt);
  scatter_edges<<<(E + 255) / 256, blk, 0, stream>>>(etgt, cursor, perm, E);
  node_mfma<<<(n_src + 63) / 64, blk, 0, stream>>>(
      h_src, W1aT, nullptr, nullptr, nullptr, A, n_src);
  node_mfma<<<(n_tgt + 63) / 64, blk, 0, stream>>>(
      h_tgt, W1bT, t_emb, W1dT, b_m1, B, n_tgt);
  edge_mfma<<<(E + EPB - 1) / EPB, blk, 0, stream>>>(
      A, B, W_m1 + 256 * 256, Wm2T, b_m2, Wc1T, b_c1, W_c2, b_c2,
      pos_src, pos_tgt, esrc, etgt, perm, agg, vel, E);
  tgt_mfma<<<(n_tgt + 63) / 64, blk, 0, stream>>>(
      h_tgt, agg, Wu1T, b_u1, Wu2T, b_u2, gamma, beta, out_h, n_tgt);
}